// Round 1
// baseline (3000.547 us; speedup 1.0000x reference)
//
#include <hip/hip_runtime.h>

// AlignmentNet: 2 branches x (cr-conv, 4x offset-conv, 4x deform-conv)
// Baseline round: straightforward f32 kernels, one per op, all on `stream`.

static constexpr int Hh = 128;
static constexpr int Ww = 128;
static constexpr int NB = 4;     // batch
static constexpr int G  = 4;     // deform groups
static constexpr int PADD = 2;   // deform pad
static constexpr int DILD = 2;   // deform dilation

// ---------------------------------------------------------------------------
// conv 3x3, pad 1, stride 1, dil 1.  Input possibly split across two tensors
// (channel concat): channels [0,cin0) from in0, [cin0,cin) from in1.
// Block: 256 threads = 16x16 spatial tile; each thread accumulates COPB couts.
// Grid: (64 tiles, cout/COPB, B)
// ---------------------------------------------------------------------------
template <int COPB>
__global__ __launch_bounds__(256) void conv3x3_kernel(
    const float* __restrict__ in0, const float* __restrict__ in1,
    int cin0, int cin,
    const float* __restrict__ w,     // (cout, cin, 3, 3)
    const float* __restrict__ bias,  // (cout)
    float* __restrict__ out, int cout) {
  const int tile = blockIdx.x;
  const int ty0 = (tile >> 3) << 4;
  const int tx0 = (tile & 7) << 4;
  const int cob = blockIdx.y * COPB;
  const int b = blockIdx.z;
  const int tid = threadIdx.x;
  const int tx = tid & 15, ty = tid >> 4;

  __shared__ float sIn[18][18];
  __shared__ float sW[COPB][9];

  float acc[COPB];
#pragma unroll
  for (int o = 0; o < COPB; ++o) acc[o] = bias[cob + o];

  const int cin1 = cin - cin0;
  for (int ci = 0; ci < cin; ++ci) {
    const float* src = (ci < cin0)
        ? in0 + (size_t)(b * cin0 + ci) * (Hh * Ww)
        : in1 + (size_t)(b * cin1 + (ci - cin0)) * (Hh * Ww);
    // stage 18x18 halo tile
    for (int i = tid; i < 18 * 18; i += 256) {
      const int r = i / 18, c = i % 18;
      const int iy = ty0 - 1 + r, ix = tx0 - 1 + c;
      float v = 0.f;
      if (iy >= 0 && iy < Hh && ix >= 0 && ix < Ww) v = src[iy * Ww + ix];
      sIn[r][c] = v;
    }
    // stage this ci's weights for COPB couts
    for (int i = tid; i < COPB * 9; i += 256) {
      sW[i / 9][i % 9] = w[((size_t)(cob + i / 9) * cin + ci) * 9 + (i % 9)];
    }
    __syncthreads();
#pragma unroll
    for (int t = 0; t < 9; ++t) {
      const float v = sIn[ty + t / 3][tx + t % 3];
#pragma unroll
      for (int o = 0; o < COPB; ++o) acc[o] = fmaf(v, sW[o][t], acc[o]);
    }
    __syncthreads();
  }
  const int y = ty0 + ty, xx = tx0 + tx;
#pragma unroll
  for (int o = 0; o < COPB; ++o)
    out[((size_t)(b * cout + cob + o) * Hh + y) * Ww + xx] = acc[o];
}

// ---------------------------------------------------------------------------
// deformable conv: x (B,64,H,W) grouped G=4 (Cg=16), offsets (B,72,H,W) laid
// out (B, G, 9, 2, H, W), weights (64,16,3,3) == (G, 16, 16, 9), K=3,
// PAD=2, DIL=2. One block = 16x16 tile of one (b, g); each thread computes
// the 16 group-outputs for its pixel.
// Grid: (64 tiles, G, B)
// ---------------------------------------------------------------------------
__global__ __launch_bounds__(256) void deform_kernel(
    const float* __restrict__ x, const float* __restrict__ off,
    const float* __restrict__ w, const float* __restrict__ bias,
    float* __restrict__ out) {
  const int tile = blockIdx.x;
  const int g = blockIdx.y, b = blockIdx.z;
  const int ty0 = (tile >> 3) << 4, tx0 = (tile & 7) << 4;
  const int tid = threadIdx.x;
  const int y = ty0 + (tid >> 4);
  const int xx = tx0 + (tid & 15);

  __shared__ float sW[16 * 16 * 9];  // [o][c][k]
  for (int i = tid; i < 16 * 16 * 9; i += 256) sW[i] = w[g * (16 * 16 * 9) + i];
  __syncthreads();

  float acc[16];
#pragma unroll
  for (int o = 0; o < 16; ++o) acc[o] = bias[g * 16 + o];

  const float* xg = x + (size_t)(b * G + g) * 16 * (Hh * Ww);
  const size_t offpix = (size_t)b * 72 * (Hh * Ww) + (size_t)y * Ww + xx;

  for (int k = 0; k < 9; ++k) {
    const int ch = (g * 9 + k) * 2;
    const float dy = off[offpix + (size_t)ch * (Hh * Ww)];
    const float dx = off[offpix + (size_t)(ch + 1) * (Hh * Ww)];
    const float py = dy + (float)(y - PADD + DILD * (k / 3));
    const float px = dx + (float)(xx - PADD + DILD * (k % 3));
    const float fy = floorf(py), fx = floorf(px);
    const int y0 = (int)fy, x0 = (int)fx;
    const int y1 = y0 + 1, x1 = x0 + 1;
    const float ly = py - fy, lx = px - fx;
    float w00 = (1.f - ly) * (1.f - lx);
    float w01 = (1.f - ly) * lx;
    float w10 = ly * (1.f - lx);
    float w11 = ly * lx;
    const bool vy0 = (y0 >= 0) && (y0 < Hh);
    const bool vy1 = (y1 >= 0) && (y1 < Hh);
    const bool vx0 = (x0 >= 0) && (x0 < Ww);
    const bool vx1 = (x1 >= 0) && (x1 < Ww);
    w00 = (vy0 && vx0) ? w00 : 0.f;
    w01 = (vy0 && vx1) ? w01 : 0.f;
    w10 = (vy1 && vx0) ? w10 : 0.f;
    w11 = (vy1 && vx1) ? w11 : 0.f;
    const int y0c = min(max(y0, 0), Hh - 1), y1c = min(max(y1, 0), Hh - 1);
    const int x0c = min(max(x0, 0), Ww - 1), x1c = min(max(x1, 0), Ww - 1);
    const int i00 = y0c * Ww + x0c, i01 = y0c * Ww + x1c;
    const int i10 = y1c * Ww + x0c, i11 = y1c * Ww + x1c;
#pragma unroll
    for (int c = 0; c < 16; ++c) {
      const float* img = xg + (size_t)c * (Hh * Ww);
      const float s = img[i00] * w00 + img[i01] * w01 +
                      img[i10] * w10 + img[i11] * w11;
#pragma unroll
      for (int o = 0; o < 16; ++o)
        acc[o] = fmaf(s, sW[o * 144 + c * 9 + k], acc[o]);
    }
  }
#pragma unroll
  for (int o = 0; o < 16; ++o)
    out[((size_t)(b * 64 + g * 16 + o) * Hh + y) * Ww + xx] = acc[o];
}

// ---------------------------------------------------------------------------

static void run_branch(const float* fr, const float* fm, void* const* d_in,
                       float* bufA, float* bufOFF, float* bufB, float* out,
                       hipStream_t stream) {
  const float* cr_w = (const float*)d_in[3];
  const float* cr_b = (const float*)d_in[4];
  const float* off1_w = (const float*)d_in[5];
  const float* off1_b = (const float*)d_in[6];
  const float* off2_w = (const float*)d_in[7];
  const float* off2_b = (const float*)d_in[8];
  const float* off3_w = (const float*)d_in[9];
  const float* off3_b = (const float*)d_in[10];
  const float* off4_w = (const float*)d_in[11];
  const float* off4_b = (const float*)d_in[12];
  const float* d1_w = (const float*)d_in[13];
  const float* d1_b = (const float*)d_in[14];
  const float* d2_w = (const float*)d_in[15];
  const float* d2_b = (const float*)d_in[16];
  const float* d3_w = (const float*)d_in[17];
  const float* d3_b = (const float*)d_in[18];
  const float* d4_w = (const float*)d_in[19];
  const float* d4_b = (const float*)d_in[20];

  const dim3 blk(256);
  const dim3 g64(64, 64 / 16, NB);  // cout=64, COPB=16
  const dim3 g72(64, 72 / 8, NB);   // cout=72, COPB=8
  const dim3 gd(64, G, NB);

  // fea = conv([fr|fm], cr)                      -> bufA
  conv3x3_kernel<16><<<g64, blk, 0, stream>>>(fr, fm, 64, 128, cr_w, cr_b,
                                              bufA, 64);
  // off = conv(fea, off1)                        -> bufOFF
  conv3x3_kernel<8><<<g72, blk, 0, stream>>>(bufA, bufA, 64, 64, off1_w,
                                             off1_b, bufOFF, 72);
  // fea = deform(fea, off, d1)                   -> bufB
  deform_kernel<<<gd, blk, 0, stream>>>(bufA, bufOFF, d1_w, d1_b, bufB);
  // off = conv(fea, off2)                        -> bufOFF
  conv3x3_kernel<8><<<g72, blk, 0, stream>>>(bufB, bufB, 64, 64, off2_w,
                                             off2_b, bufOFF, 72);
  // fea = deform(fea, off, d2)                   -> bufA
  deform_kernel<<<gd, blk, 0, stream>>>(bufB, bufOFF, d2_w, d2_b, bufA);
  // off3 = conv(fea, off3)                       -> bufOFF
  conv3x3_kernel<8><<<g72, blk, 0, stream>>>(bufA, bufA, 64, 64, off3_w,
                                             off3_b, bufOFF, 72);
  // fea = deform(fm, off3, d3)                   -> bufB
  deform_kernel<<<gd, blk, 0, stream>>>(fm, bufOFF, d3_w, d3_b, bufB);
  // off = conv(fea, off4)                        -> bufOFF
  conv3x3_kernel<8><<<g72, blk, 0, stream>>>(bufB, bufB, 64, 64, off4_w,
                                             off4_b, bufOFF, 72);
  // out = deform(fea, off, d4)                   -> out
  deform_kernel<<<gd, blk, 0, stream>>>(bufB, bufOFF, d4_w, d4_b, out);
}

extern "C" void kernel_launch(void* const* d_in, const int* in_sizes, int n_in,
                              void* d_out, int out_size, void* d_ws,
                              size_t ws_size, hipStream_t stream) {
  const float* Fref = (const float*)d_in[0];
  const float* Fmov1 = (const float*)d_in[1];
  const float* Fmov2 = (const float*)d_in[2];

  float* out0 = (float*)d_out;
  float* out1 = out0 + (size_t)NB * 64 * Hh * Ww;

  float* bufA = (float*)d_ws;
  float* bufOFF = bufA + (size_t)NB * 64 * Hh * Ww;   // 64-ch fea buffer
  float* bufB = bufOFF + (size_t)NB * 72 * Hh * Ww;   // 72-ch offset buffer

  run_branch(Fref, Fmov1, d_in, bufA, bufOFF, bufB, out0, stream);
  run_branch(Fref, Fmov2, d_in, bufA, bufOFF, bufB, out1, stream);
}

// Round 2
// 570.089 us; speedup vs baseline: 5.2633x; 5.2633x over previous
//
#include <hip/hip_runtime.h>

// AlignmentNet round 2: bf16 MFMA implicit-GEMM convs (tap-loop formulation),
// channels-last bf16 intermediates, vectorized deform with CL gathers.

using bf16x8 = __attribute__((ext_vector_type(8))) short;
using u16x8  = __attribute__((ext_vector_type(8))) unsigned short;
using f32x4  = __attribute__((ext_vector_type(4))) float;

static constexpr int Hh = 128, Ww = 128, NB = 4, NPIX = Hh * Ww;

__device__ __forceinline__ unsigned short f2bf(float f) {
  unsigned u = __float_as_uint(f);
  u += 0x7fffu + ((u >> 16) & 1u);   // round-to-nearest-even
  return (unsigned short)(u >> 16);
}
__device__ __forceinline__ float bf2f(unsigned short h) {
  return __uint_as_float(((unsigned)h) << 16);
}

// ---------------------------------------------------------------------------
// NCHW f32 (two 64-ch tensors) -> channels-last bf16 [b][pix][128]
// ---------------------------------------------------------------------------
__global__ __launch_bounds__(256) void to_cl_kernel(
    const float* __restrict__ s0, const float* __restrict__ s1,
    unsigned short* __restrict__ dst) {
  const int t = blockIdx.x * 256 + threadIdx.x;  // over NB*NPIX
  const int b = t >> 14, pix = t & (NPIX - 1);
  const float* sp0 = s0 + (size_t)b * 64 * NPIX + pix;
  const float* sp1 = s1 + (size_t)b * 64 * NPIX + pix;
  unsigned short* d = dst + (size_t)t * 128;
  for (int half = 0; half < 2; ++half) {
    const float* sp = half ? sp1 : sp0;
    for (int c8 = 0; c8 < 8; ++c8) {
      u16x8 v;
#pragma unroll
      for (int j = 0; j < 8; ++j) v[j] = f2bf(sp[(size_t)(c8 * 8 + j) * NPIX]);
      *(u16x8*)(d + half * 64 + c8 * 8) = v;
    }
  }
}

// ---------------------------------------------------------------------------
// Weight prep: (CO,CIN,3,3) f32 -> [t][co][ci] bf16, couts zero-padded to COP
// ---------------------------------------------------------------------------
__global__ __launch_bounds__(256) void prep_convw_kernel(
    const float* __restrict__ src, unsigned short* __restrict__ dst,
    int co_real, int cop, int cin) {
  const int i = blockIdx.x * 256 + threadIdx.x;
  const int n = 9 * cop * cin;
  if (i >= n) return;
  const int ci = i % cin;
  const int co = (i / cin) % cop;
  const int t = i / (cin * cop);
  float v = (co < co_real) ? src[((size_t)co * cin + ci) * 9 + t] : 0.f;
  dst[i] = f2bf(v);
}

// deform weights (64,16,3,3) f32 -> [g][k][c][o] f32 (4*9*16*16)
__global__ __launch_bounds__(256) void prep_dw_kernel(
    const float* __restrict__ src, float* __restrict__ dst) {
  const int i = blockIdx.x * 256 + threadIdx.x;
  if (i >= 4 * 9 * 16 * 16) return;
  const int o = i & 15, c = (i >> 4) & 15, k = (i >> 8) % 9, g = i / 2304;
  dst[i] = src[(size_t)((g * 16 + o) * 16 + c) * 9 + k];
}

// ---------------------------------------------------------------------------
// MFMA conv 3x3 pad 1: in CL bf16 [b][pix][CIN] -> out CL bf16 [b][pix][OST].
// Block 512 thr = 8 waves; tile 16x16 pixels; wave handles 32 pixels x all
// couts. LDS: weights [9][COP][64-ci-chunk] + input halo [324][64], both
// XOR-swizzled (^(row&7)<<4 on byte addr) for conflict-free ds_read_b128.
// ---------------------------------------------------------------------------
template <int CIN, int COP, int CO_REAL, int OST>
__global__ __launch_bounds__(512) void convmfma_kernel(
    const unsigned short* __restrict__ in,
    const unsigned short* __restrict__ wT,   // [9][COP][CIN] bf16
    const float* __restrict__ biasP,         // [CO_REAL]
    unsigned short* __restrict__ out) {
  constexpr int COF = COP / 16;
  constexpr int NCH = CIN / 64;
  __shared__ unsigned short sA[9 * COP * 64];
  __shared__ unsigned short sB[324 * 64];

  const int tile = blockIdx.x, b = blockIdx.y;
  const int ty0 = (tile >> 3) << 4, tx0 = (tile & 7) << 4;
  const int tid = threadIdx.x;
  const int wv = tid >> 6, l = tid & 63;
  const int lm = l & 15, lq = l >> 4;

  f32x4 acc[COF][2];
#pragma unroll
  for (int cf = 0; cf < COF; ++cf)
#pragma unroll
    for (int pf = 0; pf < 2; ++pf) acc[cf][pf] = (f32x4){0.f, 0.f, 0.f, 0.f};

  const unsigned short* inB = in + (size_t)b * NPIX * CIN;

  for (int ch = 0; ch < NCH; ++ch) {
    const int cinBase = ch * 64;
    // ---- stage input halo tile: [pix 0..323][ci8 0..7], swizzled
    for (int q = tid; q < 324 * 8; q += 512) {
      const int pix = q >> 3, ci8 = q & 7;
      const int r = pix / 18, c = pix - r * 18;
      const int gy = ty0 - 1 + r, gx = tx0 - 1 + c;
      u16x8 v;
      if (gy >= 0 && gy < Hh && gx >= 0 && gx < Ww) {
        v = *(const u16x8*)(inB + (size_t)(gy * Ww + gx) * CIN + cinBase +
                            ci8 * 8);
      } else {
#pragma unroll
        for (int j = 0; j < 8; ++j) v[j] = 0;
      }
      const int boff = pix * 128 + ((ci8 * 16) ^ ((pix & 7) << 4));
      *(u16x8*)((char*)sB + boff) = v;
    }
    // ---- stage weights: [t][co][ci8], swizzled by co
    for (int q = tid; q < 9 * COP * 8; q += 512) {
      const int ci8 = q & 7;
      const int co = (q >> 3) % COP;
      const int t = q / (8 * COP);
      u16x8 v = *(const u16x8*)(wT + (size_t)(t * COP + co) * CIN + cinBase +
                                ci8 * 8);
      const int aoff = (t * COP + co) * 128 + ((ci8 * 16) ^ ((co & 7) << 4));
      *(u16x8*)((char*)sA + aoff) = v;
    }
    __syncthreads();
    // ---- K loop: 9 taps x 2 k-chunks of 32
    for (int t = 0; t < 9; ++t) {
      const int dy = t / 3, dx = t - dy * 3;
#pragma unroll
      for (int kc = 0; kc < 2; ++kc) {
        bf16x8 afr[COF];
#pragma unroll
        for (int cf = 0; cf < COF; ++cf) {
          const int co = cf * 16 + lm;
          const int aoff =
              (t * COP + co) * 128 + ((kc * 64 + lq * 16) ^ ((co & 7) << 4));
          afr[cf] = *(const bf16x8*)((const char*)sA + aoff);
        }
#pragma unroll
        for (int pf = 0; pf < 2; ++pf) {
          const int pix = wv * 32 + pf * 16 + lm;
          const int spix = ((pix >> 4) + dy) * 18 + (pix & 15) + dx;
          const int boff =
              spix * 128 + ((kc * 64 + lq * 16) ^ ((spix & 7) << 4));
          const bf16x8 bfr = *(const bf16x8*)((const char*)sB + boff);
#pragma unroll
          for (int cf = 0; cf < COF; ++cf)
            acc[cf][pf] = __builtin_amdgcn_mfma_f32_16x16x32_bf16(
                afr[cf], bfr, acc[cf][pf], 0, 0, 0);
        }
      }
    }
    __syncthreads();
  }
  // ---- epilogue: +bias, pack bf16, store CL
  unsigned short* outB = out + (size_t)b * NPIX * OST;
#pragma unroll
  for (int cf = 0; cf < COF; ++cf) {
    const int co0 = cf * 16 + lq * 4;
    if (co0 >= CO_REAL) continue;
    const float4 bv = *(const float4*)(biasP + co0);
#pragma unroll
    for (int pf = 0; pf < 2; ++pf) {
      const int pix = wv * 32 + pf * 16 + lm;
      const int gpix = (ty0 + (pix >> 4)) * Ww + tx0 + (pix & 15);
      const f32x4 v = acc[cf][pf];
      ushort4 pk;
      pk.x = f2bf(v[0] + bv.x);
      pk.y = f2bf(v[1] + bv.y);
      pk.z = f2bf(v[2] + bv.z);
      pk.w = f2bf(v[3] + bv.w);
      *(ushort4*)(outB + (size_t)gpix * OST + co0) = pk;
    }
  }
}

// ---------------------------------------------------------------------------
// Deform conv v2: x CL bf16 [b][pix][XS] (group slice 16ch contiguous),
// offsets CL bf16 [b][pix][80], weights staged [k][c][o] f32.
// One block = 16x16 tile of one (b,g); thread = pixel, computes 16 outs.
// ---------------------------------------------------------------------------
__device__ __forceinline__ float vget(const u16x8& a, const u16x8& b, int c) {
  return bf2f((c < 8) ? (unsigned short)a[c] : (unsigned short)b[c - 8]);
}

template <int XS, bool NCHW_OUT>
__global__ __launch_bounds__(256) void deform2_kernel(
    const unsigned short* __restrict__ x,
    const unsigned short* __restrict__ off,  // [b][pix][80]
    const float* __restrict__ dwT,           // [4][9][16][16]
    const float* __restrict__ bias,          // [64]
    float* __restrict__ outF, unsigned short* __restrict__ outH) {
  const int tile = blockIdx.x, g = blockIdx.y, b = blockIdx.z;
  const int ty0 = (tile >> 3) << 4, tx0 = (tile & 7) << 4;
  const int tid = threadIdx.x;
  const int y = ty0 + (tid >> 4), xx = tx0 + (tid & 15);

  __shared__ float sW[9 * 16 * 16];
  for (int i = tid; i < 2304; i += 256) sW[i] = dwT[g * 2304 + i];
  __syncthreads();

  float acc[16];
#pragma unroll
  for (int o = 0; o < 16; ++o) acc[o] = bias[g * 16 + o];

  const unsigned short* xP =
      x + (size_t)b * NPIX * XS + ((XS == 128) ? 64 : 0) + g * 16;
  const unsigned short* offP =
      off + (size_t)(b * NPIX + y * Ww + xx) * 80 + g * 18;

  for (int k = 0; k < 9; ++k) {
    const unsigned odw = *(const unsigned*)(offP + 2 * k);
    const float dy = __uint_as_float(odw << 16);
    const float dx = __uint_as_float(odw & 0xffff0000u);
    const float py = dy + (float)(y - 2 + 2 * (k / 3));
    const float px = dx + (float)(xx - 2 + 2 * (k % 3));
    const float fy = floorf(py), fx = floorf(px);
    const int y0 = (int)fy, x0 = (int)fx;
    const int y1 = y0 + 1, x1 = x0 + 1;
    const float ly = py - fy, lx = px - fx;
    float w00 = (1.f - ly) * (1.f - lx), w01 = (1.f - ly) * lx;
    float w10 = ly * (1.f - lx), w11 = ly * lx;
    const bool vy0 = (y0 >= 0) && (y0 < Hh), vy1 = (y1 >= 0) && (y1 < Hh);
    const bool vx0 = (x0 >= 0) && (x0 < Ww), vx1 = (x1 >= 0) && (x1 < Ww);
    w00 = (vy0 && vx0) ? w00 : 0.f;
    w01 = (vy0 && vx1) ? w01 : 0.f;
    w10 = (vy1 && vx0) ? w10 : 0.f;
    w11 = (vy1 && vx1) ? w11 : 0.f;
    const int y0c = min(max(y0, 0), Hh - 1), y1c = min(max(y1, 0), Hh - 1);
    const int x0c = min(max(x0, 0), Ww - 1), x1c = min(max(x1, 0), Ww - 1);

    const u16x8* q00 = (const u16x8*)(xP + (size_t)(y0c * Ww + x0c) * XS);
    const u16x8* q01 = (const u16x8*)(xP + (size_t)(y0c * Ww + x1c) * XS);
    const u16x8* q10 = (const u16x8*)(xP + (size_t)(y1c * Ww + x0c) * XS);
    const u16x8* q11 = (const u16x8*)(xP + (size_t)(y1c * Ww + x1c) * XS);
    const u16x8 a00 = q00[0], b00 = q00[1];
    const u16x8 a01 = q01[0], b01 = q01[1];
    const u16x8 a10 = q10[0], b10 = q10[1];
    const u16x8 a11 = q11[0], b11 = q11[1];

#pragma unroll
    for (int c = 0; c < 16; ++c) {
      const float s = vget(a00, b00, c) * w00 + vget(a01, b01, c) * w01 +
                      vget(a10, b10, c) * w10 + vget(a11, b11, c) * w11;
      const float* wr = &sW[(k * 16 + c) * 16];
#pragma unroll
      for (int o = 0; o < 16; ++o) acc[o] = fmaf(s, wr[o], acc[o]);
    }
  }

  if (NCHW_OUT) {
    float* oB = outF + (size_t)(b * 64 + g * 16) * NPIX + y * Ww + xx;
#pragma unroll
    for (int o = 0; o < 16; ++o) oB[(size_t)o * NPIX] = acc[o];
  } else {
    unsigned short* oB = outH + (size_t)(b * NPIX + y * Ww + xx) * 64 + g * 16;
    u16x8 v0, v1;
#pragma unroll
    for (int j = 0; j < 8; ++j) {
      v0[j] = f2bf(acc[j]);
      v1[j] = f2bf(acc[8 + j]);
    }
    *(u16x8*)(oB) = v0;
    *(u16x8*)(oB + 8) = v1;
  }
}

// ---------------------------------------------------------------------------

extern "C" void kernel_launch(void* const* d_in, const int* in_sizes, int n_in,
                              void* d_out, int out_size, void* d_ws,
                              size_t ws_size, hipStream_t stream) {
  const float* Fref = (const float*)d_in[0];
  const float* Fmov1 = (const float*)d_in[1];
  const float* Fmov2 = (const float*)d_in[2];
  const float* cr_w = (const float*)d_in[3];
  const float* cr_b = (const float*)d_in[4];
  const float* offw[4] = {(const float*)d_in[5], (const float*)d_in[7],
                          (const float*)d_in[9], (const float*)d_in[11]};
  const float* offb[4] = {(const float*)d_in[6], (const float*)d_in[8],
                          (const float*)d_in[10], (const float*)d_in[12]};
  const float* dw[4] = {(const float*)d_in[13], (const float*)d_in[15],
                        (const float*)d_in[17], (const float*)d_in[19]};
  const float* db[4] = {(const float*)d_in[14], (const float*)d_in[16],
                        (const float*)d_in[18], (const float*)d_in[20]};

  float* out0 = (float*)d_out;
  float* out1 = out0 + (size_t)NB * 64 * NPIX;

  // ---- workspace carve (256B aligned)
  char* p = (char*)d_ws;
  auto carve = [&](size_t bytes) {
    void* r = p;
    p += (bytes + 255) & ~(size_t)255;
    return r;
  };
  unsigned short* crIn = (unsigned short*)carve((size_t)NB * NPIX * 128 * 2);
  unsigned short* feaA = (unsigned short*)carve((size_t)NB * NPIX * 64 * 2);
  unsigned short* feaB = (unsigned short*)carve((size_t)NB * NPIX * 64 * 2);
  unsigned short* offB = (unsigned short*)carve((size_t)NB * NPIX * 80 * 2);
  unsigned short* wcrT = (unsigned short*)carve((size_t)9 * 64 * 128 * 2);
  unsigned short* woffT[4];
  for (int i = 0; i < 4; ++i)
    woffT[i] = (unsigned short*)carve((size_t)9 * 80 * 64 * 2);
  float* dwT[4];
  for (int i = 0; i < 4; ++i) dwT[i] = (float*)carve((size_t)4 * 2304 * 4);

  // ---- weight prep (once per launch; deterministic)
  prep_convw_kernel<<<(9 * 64 * 128 + 255) / 256, 256, 0, stream>>>(
      cr_w, wcrT, 64, 64, 128);
  for (int i = 0; i < 4; ++i) {
    prep_convw_kernel<<<(9 * 80 * 64 + 255) / 256, 256, 0, stream>>>(
        offw[i], woffT[i], 72, 80, 64);
    prep_dw_kernel<<<(4 * 2304 + 255) / 256, 256, 0, stream>>>(dw[i], dwT[i]);
  }

  const dim3 cgrid(64, NB), cblk(512);
  const dim3 dgrid(64, 4, NB), dblk(256);

  for (int br = 0; br < 2; ++br) {
    const float* fm = br ? Fmov2 : Fmov1;
    float* outp = br ? out1 : out0;
    // crIn = CL bf16 [Fref | Fmov]
    to_cl_kernel<<<NB * NPIX / 256, 256, 0, stream>>>(Fref, fm, crIn);
    // fea = conv(crIn, cr)                -> feaA
    convmfma_kernel<128, 64, 64, 64>
        <<<cgrid, cblk, 0, stream>>>(crIn, wcrT, cr_b, feaA);
    // off1; fea = deform(feaA, off1, d1)  -> feaB
    convmfma_kernel<64, 80, 72, 80>
        <<<cgrid, cblk, 0, stream>>>(feaA, woffT[0], offb[0], offB);
    deform2_kernel<64, false>
        <<<dgrid, dblk, 0, stream>>>(feaA, offB, dwT[0], db[0], nullptr, feaB);
    // off2; fea = deform(feaB, off2, d2)  -> feaA
    convmfma_kernel<64, 80, 72, 80>
        <<<cgrid, cblk, 0, stream>>>(feaB, woffT[1], offb[1], offB);
    deform2_kernel<64, false>
        <<<dgrid, dblk, 0, stream>>>(feaB, offB, dwT[1], db[1], nullptr, feaA);
    // off3 from feaA; fea = deform(fm(bf16, crIn hi-half), off3, d3) -> feaB
    convmfma_kernel<64, 80, 72, 80>
        <<<cgrid, cblk, 0, stream>>>(feaA, woffT[2], offb[2], offB);
    deform2_kernel<128, false>
        <<<dgrid, dblk, 0, stream>>>(crIn, offB, dwT[2], db[2], nullptr, feaB);
    // off4; out = deform(feaB, off4, d4)  -> d_out (f32 NCHW)
    convmfma_kernel<64, 80, 72, 80>
        <<<cgrid, cblk, 0, stream>>>(feaB, woffT[3], offb[3], offB);
    deform2_kernel<64, true>
        <<<dgrid, dblk, 0, stream>>>(feaB, offB, dwT[3], db[3], outp, nullptr);
  }
}

// Round 3
// 496.228 us; speedup vs baseline: 6.0467x; 1.1488x over previous
//
#include <hip/hip_runtime.h>

// AlignmentNet round 3: MFMA deform (sample->LDS->mfma, barrier-free),
// bf16 MFMA convs, channels-last bf16 intermediates.

using bf16x8 = __attribute__((ext_vector_type(8))) short;
using u16x8  = __attribute__((ext_vector_type(8))) unsigned short;
using f32x4  = __attribute__((ext_vector_type(4))) float;

static constexpr int Hh = 128, Ww = 128, NB = 4, NPIX = Hh * Ww;

__device__ __forceinline__ unsigned short f2bf(float f) {
  unsigned u = __float_as_uint(f);
  u += 0x7fffu + ((u >> 16) & 1u);   // round-to-nearest-even
  return (unsigned short)(u >> 16);
}
__device__ __forceinline__ float bf2f(unsigned short h) {
  return __uint_as_float(((unsigned)h) << 16);
}

// ---------------------------------------------------------------------------
// NCHW f32 (two 64-ch tensors) -> channels-last bf16 [b][pix][128]
// ---------------------------------------------------------------------------
__global__ __launch_bounds__(256) void to_cl_kernel(
    const float* __restrict__ s0, const float* __restrict__ s1,
    unsigned short* __restrict__ dst) {
  const int t = blockIdx.x * 256 + threadIdx.x;  // over NB*NPIX
  const int b = t >> 14, pix = t & (NPIX - 1);
  const float* sp0 = s0 + (size_t)b * 64 * NPIX + pix;
  const float* sp1 = s1 + (size_t)b * 64 * NPIX + pix;
  unsigned short* d = dst + (size_t)t * 128;
  for (int half = 0; half < 2; ++half) {
    const float* sp = half ? sp1 : sp0;
    for (int c8 = 0; c8 < 8; ++c8) {
      u16x8 v;
#pragma unroll
      for (int j = 0; j < 8; ++j) v[j] = f2bf(sp[(size_t)(c8 * 8 + j) * NPIX]);
      *(u16x8*)(d + half * 64 + c8 * 8) = v;
    }
  }
}

// ---------------------------------------------------------------------------
// Weight prep: (CO,CIN,3,3) f32 -> [t][co][ci] bf16, couts zero-padded to COP
// ---------------------------------------------------------------------------
__global__ __launch_bounds__(256) void prep_convw_kernel(
    const float* __restrict__ src, unsigned short* __restrict__ dst,
    int co_real, int cop, int cin) {
  const int i = blockIdx.x * 256 + threadIdx.x;
  const int n = 9 * cop * cin;
  if (i >= n) return;
  const int ci = i % cin;
  const int co = (i / cin) % cop;
  const int t = i / (cin * cop);
  float v = (co < co_real) ? src[((size_t)co * cin + ci) * 9 + t] : 0.f;
  dst[i] = f2bf(v);
}

// deform weights (64,16,3,3) -> MFMA A layout [g][pair][o][kk] bf16,
// kk = tap_in_pair*16 + c, tap = pair*2 + (kk>>4); tap 9 zero-padded.
__global__ __launch_bounds__(256) void prep_dwmfma_kernel(
    const float* __restrict__ src, unsigned short* __restrict__ dst) {
  const int i = blockIdx.x * 256 + threadIdx.x;
  if (i >= 4 * 5 * 16 * 32) return;
  const int kk = i & 31;
  const int o = (i >> 5) & 15;
  const int pair = (i >> 9) % 5;
  const int g = i / (5 * 16 * 32);
  const int t = pair * 2 + (kk >> 4);
  const int c = kk & 15;
  float v = (t < 9) ? src[(size_t)((g * 16 + o) * 16 + c) * 9 + t] : 0.f;
  dst[i] = f2bf(v);
}

// ---------------------------------------------------------------------------
// MFMA conv 3x3 pad 1: in CL bf16 [b][pix][CIN] -> out CL bf16 [b][pix][OST].
// ---------------------------------------------------------------------------
template <int CIN, int COP, int CO_REAL, int OST>
__global__ __launch_bounds__(512) void convmfma_kernel(
    const unsigned short* __restrict__ in,
    const unsigned short* __restrict__ wT,   // [9][COP][CIN] bf16
    const float* __restrict__ biasP,         // [CO_REAL]
    unsigned short* __restrict__ out) {
  constexpr int COF = COP / 16;
  constexpr int NCH = CIN / 64;
  __shared__ unsigned short sA[9 * COP * 64];
  __shared__ unsigned short sB[324 * 64];

  const int tile = blockIdx.x, b = blockIdx.y;
  const int ty0 = (tile >> 3) << 4, tx0 = (tile & 7) << 4;
  const int tid = threadIdx.x;
  const int wv = tid >> 6, l = tid & 63;
  const int lm = l & 15, lq = l >> 4;

  f32x4 acc[COF][2];
#pragma unroll
  for (int cf = 0; cf < COF; ++cf)
#pragma unroll
    for (int pf = 0; pf < 2; ++pf) acc[cf][pf] = (f32x4){0.f, 0.f, 0.f, 0.f};

  const unsigned short* inB = in + (size_t)b * NPIX * CIN;

  for (int ch = 0; ch < NCH; ++ch) {
    const int cinBase = ch * 64;
    for (int q = tid; q < 324 * 8; q += 512) {
      const int pix = q >> 3, ci8 = q & 7;
      const int r = pix / 18, c = pix - r * 18;
      const int gy = ty0 - 1 + r, gx = tx0 - 1 + c;
      u16x8 v;
      if (gy >= 0 && gy < Hh && gx >= 0 && gx < Ww) {
        v = *(const u16x8*)(inB + (size_t)(gy * Ww + gx) * CIN + cinBase +
                            ci8 * 8);
      } else {
#pragma unroll
        for (int j = 0; j < 8; ++j) v[j] = 0;
      }
      const int boff = pix * 128 + ((ci8 * 16) ^ ((pix & 7) << 4));
      *(u16x8*)((char*)sB + boff) = v;
    }
    for (int q = tid; q < 9 * COP * 8; q += 512) {
      const int ci8 = q & 7;
      const int co = (q >> 3) % COP;
      const int t = q / (8 * COP);
      u16x8 v = *(const u16x8*)(wT + (size_t)(t * COP + co) * CIN + cinBase +
                                ci8 * 8);
      const int aoff = (t * COP + co) * 128 + ((ci8 * 16) ^ ((co & 7) << 4));
      *(u16x8*)((char*)sA + aoff) = v;
    }
    __syncthreads();
    for (int t = 0; t < 9; ++t) {
      const int dy = t / 3, dx = t - dy * 3;
#pragma unroll
      for (int kc = 0; kc < 2; ++kc) {
        bf16x8 afr[COF];
#pragma unroll
        for (int cf = 0; cf < COF; ++cf) {
          const int co = cf * 16 + lm;
          const int aoff =
              (t * COP + co) * 128 + ((kc * 64 + lq * 16) ^ ((co & 7) << 4));
          afr[cf] = *(const bf16x8*)((const char*)sA + aoff);
        }
#pragma unroll
        for (int pf = 0; pf < 2; ++pf) {
          const int pix = wv * 32 + pf * 16 + lm;
          const int spix = ((pix >> 4) + dy) * 18 + (pix & 15) + dx;
          const int boff =
              spix * 128 + ((kc * 64 + lq * 16) ^ ((spix & 7) << 4));
          const bf16x8 bfr = *(const bf16x8*)((const char*)sB + boff);
#pragma unroll
          for (int cf = 0; cf < COF; ++cf)
            acc[cf][pf] = __builtin_amdgcn_mfma_f32_16x16x32_bf16(
                afr[cf], bfr, acc[cf][pf], 0, 0, 0);
        }
      }
    }
    __syncthreads();
  }
  unsigned short* outB = out + (size_t)b * NPIX * OST;
#pragma unroll
  for (int cf = 0; cf < COF; ++cf) {
    const int co0 = cf * 16 + lq * 4;
    if (co0 >= CO_REAL) continue;
    const float4 bv = *(const float4*)(biasP + co0);
#pragma unroll
    for (int pf = 0; pf < 2; ++pf) {
      const int pix = wv * 32 + pf * 16 + lm;
      const int gpix = (ty0 + (pix >> 4)) * Ww + tx0 + (pix & 15);
      const f32x4 v = acc[cf][pf];
      ushort4 pk;
      pk.x = f2bf(v[0] + bv.x);
      pk.y = f2bf(v[1] + bv.y);
      pk.z = f2bf(v[2] + bv.z);
      pk.w = f2bf(v[3] + bv.w);
      *(ushort4*)(outB + (size_t)gpix * OST + co0) = pk;
    }
  }
}

// ---------------------------------------------------------------------------
// MFMA deform: thread = pixel samples 16 channels per tap (bilinear, bf16),
// writes K-chunks (tap-pairs, K=32) to LDS [pix][32k] stride 80B; each wave
// mfma's its own 64 pixels x 16 outs. No __syncthreads (wave-local LDS use).
// Grid: (64 tiles, G, B), block 256.
// ---------------------------------------------------------------------------
__device__ __forceinline__ float vget(const u16x8& a, const u16x8& b, int c) {
  return bf2f((c < 8) ? (unsigned short)a[c] : (unsigned short)b[c - 8]);
}

template <int XS, bool NCHW_OUT>
__global__ __launch_bounds__(256) void deform3_kernel(
    const unsigned short* __restrict__ x,
    const unsigned short* __restrict__ off,  // [b][pix][80] bf16
    const unsigned short* __restrict__ dwP,  // [4][5][16][32] bf16
    const float* __restrict__ bias,          // [64]
    float* __restrict__ outF, unsigned short* __restrict__ outH) {
  __shared__ char sB[256 * 80];
  const int tile = blockIdx.x, g = blockIdx.y, b = blockIdx.z;
  const int ty0 = (tile >> 3) << 4, tx0 = (tile & 7) << 4;
  const int tid = threadIdx.x;
  const int l = tid & 63, wv = tid >> 6;
  const int lm = l & 15, lq = l >> 4;
  const int y = ty0 + (tid >> 4), xx = tx0 + (tid & 15);

  // A fragments (weights) in registers: o = lm, k0 = lq*8
  bf16x8 afr[5];
#pragma unroll
  for (int p = 0; p < 5; ++p)
    afr[p] = *(const bf16x8*)(dwP + ((size_t)(g * 5 + p) * 16 + lm) * 32 +
                              lq * 8);

  f32x4 acc[4];
#pragma unroll
  for (int n = 0; n < 4; ++n) acc[n] = (f32x4){0.f, 0.f, 0.f, 0.f};

  const unsigned short* xP =
      x + (size_t)b * NPIX * XS + ((XS == 128) ? 64 : 0) + g * 16;
  const unsigned short* offP =
      off + (size_t)(b * NPIX + y * Ww + xx) * 80 + g * 18;
  char* myB = sB + tid * 80;

#pragma unroll
  for (int pair = 0; pair < 5; ++pair) {
#pragma unroll
    for (int ti = 0; ti < 2; ++ti) {
      constexpr int dummy = 0;
      const int t = pair * 2 + ti;
      u16x8 s0, s1;
#pragma unroll
      for (int j = 0; j < 8; ++j) { s0[j] = 0; s1[j] = 0; }
      if (t < 9) {
        const unsigned odw = *(const unsigned*)(offP + 2 * t);
        const float dy = __uint_as_float(odw << 16);
        const float dx = __uint_as_float(odw & 0xffff0000u);
        const float py = dy + (float)(y - 2 + 2 * (t / 3));
        const float px = dx + (float)(xx - 2 + 2 * (t % 3));
        const float fy = floorf(py), fx = floorf(px);
        const int y0 = (int)fy, x0 = (int)fx;
        const int y1 = y0 + 1, x1 = x0 + 1;
        const float ly = py - fy, lx = px - fx;
        float w00 = (1.f - ly) * (1.f - lx), w01 = (1.f - ly) * lx;
        float w10 = ly * (1.f - lx), w11 = ly * lx;
        const bool vy0 = (y0 >= 0) && (y0 < Hh), vy1 = (y1 >= 0) && (y1 < Hh);
        const bool vx0 = (x0 >= 0) && (x0 < Ww), vx1 = (x1 >= 0) && (x1 < Ww);
        w00 = (vy0 && vx0) ? w00 : 0.f;
        w01 = (vy0 && vx1) ? w01 : 0.f;
        w10 = (vy1 && vx0) ? w10 : 0.f;
        w11 = (vy1 && vx1) ? w11 : 0.f;
        const int y0c = min(max(y0, 0), Hh - 1), y1c = min(max(y1, 0), Hh - 1);
        const int x0c = min(max(x0, 0), Ww - 1), x1c = min(max(x1, 0), Ww - 1);
        const u16x8* q00 = (const u16x8*)(xP + (size_t)(y0c * Ww + x0c) * XS);
        const u16x8* q01 = (const u16x8*)(xP + (size_t)(y0c * Ww + x1c) * XS);
        const u16x8* q10 = (const u16x8*)(xP + (size_t)(y1c * Ww + x0c) * XS);
        const u16x8* q11 = (const u16x8*)(xP + (size_t)(y1c * Ww + x1c) * XS);
        const u16x8 a00 = q00[0], b00 = q00[1];
        const u16x8 a01 = q01[0], b01 = q01[1];
        const u16x8 a10 = q10[0], b10 = q10[1];
        const u16x8 a11 = q11[0], b11 = q11[1];
#pragma unroll
        for (int c = 0; c < 8; ++c) {
          const float s = vget(a00, b00, c) * w00 + vget(a01, b01, c) * w01 +
                          vget(a10, b10, c) * w10 + vget(a11, b11, c) * w11;
          s0[c] = f2bf(s);
        }
#pragma unroll
        for (int c = 8; c < 16; ++c) {
          const float s = vget(a00, b00, c) * w00 + vget(a01, b01, c) * w01 +
                          vget(a10, b10, c) * w10 + vget(a11, b11, c) * w11;
          s1[c - 8] = f2bf(s);
        }
      }
      (void)dummy;
      *(u16x8*)(myB + ti * 32) = s0;
      *(u16x8*)(myB + ti * 32 + 16) = s1;
    }
    // MFMA over this K=32 chunk: wave-local pixels, no barrier needed.
#pragma unroll
    for (int n = 0; n < 4; ++n) {
      const bf16x8 bfr =
          *(const bf16x8*)(sB + (wv * 64 + n * 16 + lm) * 80 + lq * 16);
      acc[n] = __builtin_amdgcn_mfma_f32_16x16x32_bf16(afr[pair], bfr, acc[n],
                                                       0, 0, 0);
    }
  }

  // epilogue: +bias; C layout col(pixel)=lm, row(out)=lq*4+r
  const float4 bv = *(const float4*)(bias + g * 16 + lq * 4);
#pragma unroll
  for (int n = 0; n < 4; ++n) {
    const int pixl = wv * 64 + n * 16 + lm;
    const int gpix = (ty0 + (pixl >> 4)) * Ww + tx0 + (pixl & 15);
    const f32x4 v = acc[n];
    if (NCHW_OUT) {
      float* oB = outF + (size_t)(b * 64 + g * 16 + lq * 4) * NPIX + gpix;
      oB[0] = v[0] + bv.x;
      oB[NPIX] = v[1] + bv.y;
      oB[2 * NPIX] = v[2] + bv.z;
      oB[3 * NPIX] = v[3] + bv.w;
    } else {
      ushort4 pk;
      pk.x = f2bf(v[0] + bv.x);
      pk.y = f2bf(v[1] + bv.y);
      pk.z = f2bf(v[2] + bv.z);
      pk.w = f2bf(v[3] + bv.w);
      *(ushort4*)(outH + (size_t)(b * NPIX + gpix) * 64 + g * 16 + lq * 4) = pk;
    }
  }
}

// ---------------------------------------------------------------------------

extern "C" void kernel_launch(void* const* d_in, const int* in_sizes, int n_in,
                              void* d_out, int out_size, void* d_ws,
                              size_t ws_size, hipStream_t stream) {
  const float* Fref = (const float*)d_in[0];
  const float* Fmov1 = (const float*)d_in[1];
  const float* Fmov2 = (const float*)d_in[2];
  const float* cr_w = (const float*)d_in[3];
  const float* cr_b = (const float*)d_in[4];
  const float* offw[4] = {(const float*)d_in[5], (const float*)d_in[7],
                          (const float*)d_in[9], (const float*)d_in[11]};
  const float* offb[4] = {(const float*)d_in[6], (const float*)d_in[8],
                          (const float*)d_in[10], (const float*)d_in[12]};
  const float* dw[4] = {(const float*)d_in[13], (const float*)d_in[15],
                        (const float*)d_in[17], (const float*)d_in[19]};
  const float* db[4] = {(const float*)d_in[14], (const float*)d_in[16],
                        (const float*)d_in[18], (const float*)d_in[20]};

  float* out0 = (float*)d_out;
  float* out1 = out0 + (size_t)NB * 64 * NPIX;

  char* p = (char*)d_ws;
  auto carve = [&](size_t bytes) {
    void* r = p;
    p += (bytes + 255) & ~(size_t)255;
    return r;
  };
  unsigned short* crIn = (unsigned short*)carve((size_t)NB * NPIX * 128 * 2);
  unsigned short* feaA = (unsigned short*)carve((size_t)NB * NPIX * 64 * 2);
  unsigned short* feaB = (unsigned short*)carve((size_t)NB * NPIX * 64 * 2);
  unsigned short* offB = (unsigned short*)carve((size_t)NB * NPIX * 80 * 2);
  unsigned short* wcrT = (unsigned short*)carve((size_t)9 * 64 * 128 * 2);
  unsigned short* woffT[4];
  for (int i = 0; i < 4; ++i)
    woffT[i] = (unsigned short*)carve((size_t)9 * 80 * 64 * 2);
  unsigned short* dwP[4];
  for (int i = 0; i < 4; ++i)
    dwP[i] = (unsigned short*)carve((size_t)4 * 5 * 16 * 32 * 2);

  prep_convw_kernel<<<(9 * 64 * 128 + 255) / 256, 256, 0, stream>>>(
      cr_w, wcrT, 64, 64, 128);
  for (int i = 0; i < 4; ++i) {
    prep_convw_kernel<<<(9 * 80 * 64 + 255) / 256, 256, 0, stream>>>(
        offw[i], woffT[i], 72, 80, 64);
    prep_dwmfma_kernel<<<(4 * 5 * 16 * 32 + 255) / 256, 256, 0, stream>>>(
        dw[i], dwP[i]);
  }

  const dim3 cgrid(64, NB), cblk(512);
  const dim3 dgrid(64, 4, NB), dblk(256);

  for (int br = 0; br < 2; ++br) {
    const float* fm = br ? Fmov2 : Fmov1;
    float* outp = br ? out1 : out0;
    to_cl_kernel<<<NB * NPIX / 256, 256, 0, stream>>>(Fref, fm, crIn);
    convmfma_kernel<128, 64, 64, 64>
        <<<cgrid, cblk, 0, stream>>>(crIn, wcrT, cr_b, feaA);
    convmfma_kernel<64, 80, 72, 80>
        <<<cgrid, cblk, 0, stream>>>(feaA, woffT[0], offb[0], offB);
    deform3_kernel<64, false>
        <<<dgrid, dblk, 0, stream>>>(feaA, offB, dwP[0], db[0], nullptr, feaB);
    convmfma_kernel<64, 80, 72, 80>
        <<<cgrid, cblk, 0, stream>>>(feaB, woffT[1], offb[1], offB);
    deform3_kernel<64, false>
        <<<dgrid, dblk, 0, stream>>>(feaB, offB, dwP[1], db[1], nullptr, feaA);
    convmfma_kernel<64, 80, 72, 80>
        <<<cgrid, cblk, 0, stream>>>(feaA, woffT[2], offb[2], offB);
    deform3_kernel<128, false>
        <<<dgrid, dblk, 0, stream>>>(crIn, offB, dwP[2], db[2], nullptr, feaB);
    convmfma_kernel<64, 80, 72, 80>
        <<<cgrid, cblk, 0, stream>>>(feaB, woffT[3], offb[3], offB);
    deform3_kernel<64, true>
        <<<dgrid, dblk, 0, stream>>>(feaB, offB, dwP[3], db[3], outp, nullptr);
  }
}

// Round 4
// 368.648 us; speedup vs baseline: 8.1393x; 1.3461x over previous
//
#include <hip/hip_runtime.h>

// AlignmentNet round 4: group-split channels-last fea layout [b][g][pix][16]
// (L1-resident deform gathers), 128-VGPR deform with hoisted offset loads.

using bf16x8 = __attribute__((ext_vector_type(8))) short;
using u16x8  = __attribute__((ext_vector_type(8))) unsigned short;
using f32x4  = __attribute__((ext_vector_type(4))) float;

static constexpr int Hh = 128, Ww = 128, NB = 4, NPIX = Hh * Ww;

__device__ __forceinline__ unsigned short f2bf(float f) {
  unsigned u = __float_as_uint(f);
  u += 0x7fffu + ((u >> 16) & 1u);   // round-to-nearest-even
  return (unsigned short)(u >> 16);
}
__device__ __forceinline__ float bf2f(unsigned short h) {
  return __uint_as_float(((unsigned)h) << 16);
}

// ---------------------------------------------------------------------------
// NCHW f32 -> (a) CL bf16 [b][pix][128] = [Fref|Fmov] for the cr conv,
//             (b) group-split bf16 [b][g][pix][16] of Fmov for deform d3.
// ---------------------------------------------------------------------------
__global__ __launch_bounds__(256) void to_cl_kernel(
    const float* __restrict__ s0, const float* __restrict__ s1,
    unsigned short* __restrict__ dst, unsigned short* __restrict__ gs) {
  const int t = blockIdx.x * 256 + threadIdx.x;  // over NB*NPIX
  const int b = t >> 14, pix = t & (NPIX - 1);
  const float* sp0 = s0 + (size_t)b * 64 * NPIX + pix;
  const float* sp1 = s1 + (size_t)b * 64 * NPIX + pix;
  unsigned short* d = dst + (size_t)t * 128;
  for (int half = 0; half < 2; ++half) {
    const float* sp = half ? sp1 : sp0;
    for (int c8 = 0; c8 < 8; ++c8) {
      u16x8 v;
#pragma unroll
      for (int j = 0; j < 8; ++j) v[j] = f2bf(sp[(size_t)(c8 * 8 + j) * NPIX]);
      *(u16x8*)(d + half * 64 + c8 * 8) = v;
      if (half == 1) {
        const int g = c8 >> 1;
        *(u16x8*)(gs + ((size_t)(b * 4 + g) * NPIX + pix) * 16 +
                  (c8 & 1) * 8) = v;
      }
    }
  }
}

// ---------------------------------------------------------------------------
// Weight prep: (CO,CIN,3,3) f32 -> [t][co][ci] bf16, couts zero-padded to COP
// ---------------------------------------------------------------------------
__global__ __launch_bounds__(256) void prep_convw_kernel(
    const float* __restrict__ src, unsigned short* __restrict__ dst,
    int co_real, int cop, int cin) {
  const int i = blockIdx.x * 256 + threadIdx.x;
  const int n = 9 * cop * cin;
  if (i >= n) return;
  const int ci = i % cin;
  const int co = (i / cin) % cop;
  const int t = i / (cin * cop);
  float v = (co < co_real) ? src[((size_t)co * cin + ci) * 9 + t] : 0.f;
  dst[i] = f2bf(v);
}

// deform weights (64,16,3,3) -> MFMA A layout [g][pair][o][kk] bf16,
// kk = tap_in_pair*16 + c, tap = pair*2 + (kk>>4); tap 9 zero-padded.
__global__ __launch_bounds__(256) void prep_dwmfma_kernel(
    const float* __restrict__ src, unsigned short* __restrict__ dst) {
  const int i = blockIdx.x * 256 + threadIdx.x;
  if (i >= 4 * 5 * 16 * 32) return;
  const int kk = i & 31;
  const int o = (i >> 5) & 15;
  const int pair = (i >> 9) % 5;
  const int g = i / (5 * 16 * 32);
  const int t = pair * 2 + (kk >> 4);
  const int c = kk & 15;
  float v = (t < 9) ? src[(size_t)((g * 16 + o) * 16 + c) * 9 + t] : 0.f;
  dst[i] = f2bf(v);
}

// ---------------------------------------------------------------------------
// MFMA conv 3x3 pad 1. IN_GS: input is [b][g][pix][16]; else [b][pix][CIN].
// OUT_GS: output group-split [b][g][pix][16]; else pixel-major [b][pix][OST].
// ---------------------------------------------------------------------------
template <int CIN, int COP, int CO_REAL, int OST, bool IN_GS, bool OUT_GS>
__global__ __launch_bounds__(512) void convmfma_kernel(
    const unsigned short* __restrict__ in,
    const unsigned short* __restrict__ wT,   // [9][COP][CIN] bf16
    const float* __restrict__ biasP,         // [CO_REAL]
    unsigned short* __restrict__ out) {
  constexpr int COF = COP / 16;
  constexpr int NCH = CIN / 64;
  __shared__ unsigned short sA[9 * COP * 64];
  __shared__ unsigned short sB[324 * 64];

  const int tile = blockIdx.x, b = blockIdx.y;
  const int ty0 = (tile >> 3) << 4, tx0 = (tile & 7) << 4;
  const int tid = threadIdx.x;
  const int wv = tid >> 6, l = tid & 63;
  const int lm = l & 15, lq = l >> 4;

  f32x4 acc[COF][2];
#pragma unroll
  for (int cf = 0; cf < COF; ++cf)
#pragma unroll
    for (int pf = 0; pf < 2; ++pf) acc[cf][pf] = (f32x4){0.f, 0.f, 0.f, 0.f};

  const unsigned short* inB =
      IN_GS ? in + (size_t)b * 4 * NPIX * 16 : in + (size_t)b * NPIX * CIN;

  for (int ch = 0; ch < NCH; ++ch) {
    const int cinBase = ch * 64;
    for (int q = tid; q < 324 * 8; q += 512) {
      const int pix = q >> 3, ci8 = q & 7;
      const int r = pix / 18, c = pix - r * 18;
      const int gy = ty0 - 1 + r, gx = tx0 - 1 + c;
      u16x8 v;
      if (gy >= 0 && gy < Hh && gx >= 0 && gx < Ww) {
        if (IN_GS)
          v = *(const u16x8*)(inB + ((size_t)(ci8 >> 1) * NPIX + gy * Ww + gx) *
                                        16 + (ci8 & 1) * 8);
        else
          v = *(const u16x8*)(inB + (size_t)(gy * Ww + gx) * CIN + cinBase +
                              ci8 * 8);
      } else {
#pragma unroll
        for (int j = 0; j < 8; ++j) v[j] = 0;
      }
      const int boff = pix * 128 + ((ci8 * 16) ^ ((pix & 7) << 4));
      *(u16x8*)((char*)sB + boff) = v;
    }
    for (int q = tid; q < 9 * COP * 8; q += 512) {
      const int ci8 = q & 7;
      const int co = (q >> 3) % COP;
      const int t = q / (8 * COP);
      u16x8 v = *(const u16x8*)(wT + (size_t)(t * COP + co) * CIN + cinBase +
                                ci8 * 8);
      const int aoff = (t * COP + co) * 128 + ((ci8 * 16) ^ ((co & 7) << 4));
      *(u16x8*)((char*)sA + aoff) = v;
    }
    __syncthreads();
    for (int t = 0; t < 9; ++t) {
      const int dy = t / 3, dx = t - dy * 3;
#pragma unroll
      for (int kc = 0; kc < 2; ++kc) {
        bf16x8 afr[COF];
#pragma unroll
        for (int cf = 0; cf < COF; ++cf) {
          const int co = cf * 16 + lm;
          const int aoff =
              (t * COP + co) * 128 + ((kc * 64 + lq * 16) ^ ((co & 7) << 4));
          afr[cf] = *(const bf16x8*)((const char*)sA + aoff);
        }
#pragma unroll
        for (int pf = 0; pf < 2; ++pf) {
          const int pix = wv * 32 + pf * 16 + lm;
          const int spix = ((pix >> 4) + dy) * 18 + (pix & 15) + dx;
          const int boff =
              spix * 128 + ((kc * 64 + lq * 16) ^ ((spix & 7) << 4));
          const bf16x8 bfr = *(const bf16x8*)((const char*)sB + boff);
#pragma unroll
          for (int cf = 0; cf < COF; ++cf)
            acc[cf][pf] = __builtin_amdgcn_mfma_f32_16x16x32_bf16(
                afr[cf], bfr, acc[cf][pf], 0, 0, 0);
        }
      }
    }
    __syncthreads();
  }
  unsigned short* outB = out + (size_t)b * NPIX * OST;
#pragma unroll
  for (int cf = 0; cf < COF; ++cf) {
    const int co0 = cf * 16 + lq * 4;
    if (co0 >= CO_REAL) continue;
    const float4 bv = *(const float4*)(biasP + co0);
#pragma unroll
    for (int pf = 0; pf < 2; ++pf) {
      const int pix = wv * 32 + pf * 16 + lm;
      const int gpix = (ty0 + (pix >> 4)) * Ww + tx0 + (pix & 15);
      const f32x4 v = acc[cf][pf];
      ushort4 pk;
      pk.x = f2bf(v[0] + bv.x);
      pk.y = f2bf(v[1] + bv.y);
      pk.z = f2bf(v[2] + bv.z);
      pk.w = f2bf(v[3] + bv.w);
      if (OUT_GS)
        *(ushort4*)(out + ((size_t)(b * 4 + cf) * NPIX + gpix) * 16 + lq * 4) =
            pk;
      else
        *(ushort4*)(outB + (size_t)gpix * OST + co0) = pk;
    }
  }
}

// ---------------------------------------------------------------------------
// MFMA deform: x group-split [b][g][pix][16] bf16 (one 32B line per gather).
// Thread = pixel; bilinear-samples 16 ch/tap, writes K=32 chunks (tap pairs)
// to LDS [pix][32k] stride 80B; wave mfma's its own 64 pixels (no barrier).
// Grid: (64 tiles, G, B), block 256; 128-VGPR budget for load pipelining.
// ---------------------------------------------------------------------------
__device__ __forceinline__ float vget(const u16x8& a, const u16x8& b, int c) {
  return bf2f((c < 8) ? (unsigned short)a[c] : (unsigned short)b[c - 8]);
}

template <bool NCHW_OUT>
__global__ __launch_bounds__(256, 4) void deform4_kernel(
    const unsigned short* __restrict__ x,    // [b][g][pix][16] bf16
    const unsigned short* __restrict__ off,  // [b][pix][80] bf16
    const unsigned short* __restrict__ dwP,  // [4][5][16][32] bf16
    const float* __restrict__ bias,          // [64]
    float* __restrict__ outF, unsigned short* __restrict__ outH) {
  __shared__ char sB[256 * 80];
  const int tile = blockIdx.x, g = blockIdx.y, b = blockIdx.z;
  const int ty0 = (tile >> 3) << 4, tx0 = (tile & 7) << 4;
  const int tid = threadIdx.x;
  const int l = tid & 63, wv = tid >> 6;
  const int lm = l & 15, lq = l >> 4;
  const int y = ty0 + (tid >> 4), xx = tx0 + (tid & 15);

  // A fragments (weights) in registers: o = lm, k0 = lq*8
  bf16x8 afr[5];
#pragma unroll
  for (int p = 0; p < 5; ++p)
    afr[p] = *(const bf16x8*)(dwP + ((size_t)(g * 5 + p) * 16 + lm) * 32 +
                              lq * 8);

  f32x4 acc[4];
#pragma unroll
  for (int n = 0; n < 4; ++n) acc[n] = (f32x4){0.f, 0.f, 0.f, 0.f};

  const unsigned short* xP = x + (size_t)(b * 4 + g) * NPIX * 16;
  const unsigned short* offP =
      off + (size_t)(b * NPIX + y * Ww + xx) * 80 + g * 18;
  char* myB = sB + tid * 80;

  // hoist all 9 offset dwords
  unsigned od[9];
#pragma unroll
  for (int t = 0; t < 9; ++t) od[t] = *(const unsigned*)(offP + 2 * t);

#pragma unroll
  for (int pair = 0; pair < 5; ++pair) {
#pragma unroll
    for (int ti = 0; ti < 2; ++ti) {
      const int t = pair * 2 + ti;
      u16x8 s0, s1;
#pragma unroll
      for (int j = 0; j < 8; ++j) { s0[j] = 0; s1[j] = 0; }
      if (t < 9) {
        const unsigned odw = od[t < 9 ? t : 0];
        const float dy = __uint_as_float(odw << 16);
        const float dx = __uint_as_float(odw & 0xffff0000u);
        const float py = dy + (float)(y - 2 + 2 * (t / 3));
        const float px = dx + (float)(xx - 2 + 2 * (t % 3));
        const float fy = floorf(py), fx = floorf(px);
        const int y0 = (int)fy, x0 = (int)fx;
        const int y1 = y0 + 1, x1 = x0 + 1;
        const float ly = py - fy, lx = px - fx;
        float w00 = (1.f - ly) * (1.f - lx), w01 = (1.f - ly) * lx;
        float w10 = ly * (1.f - lx), w11 = ly * lx;
        const bool vy0 = (y0 >= 0) && (y0 < Hh), vy1 = (y1 >= 0) && (y1 < Hh);
        const bool vx0 = (x0 >= 0) && (x0 < Ww), vx1 = (x1 >= 0) && (x1 < Ww);
        w00 = (vy0 && vx0) ? w00 : 0.f;
        w01 = (vy0 && vx1) ? w01 : 0.f;
        w10 = (vy1 && vx0) ? w10 : 0.f;
        w11 = (vy1 && vx1) ? w11 : 0.f;
        const int y0c = min(max(y0, 0), Hh - 1), y1c = min(max(y1, 0), Hh - 1);
        const int x0c = min(max(x0, 0), Ww - 1), x1c = min(max(x1, 0), Ww - 1);
        const u16x8* q00 = (const u16x8*)(xP + (size_t)(y0c * Ww + x0c) * 16);
        const u16x8* q01 = (const u16x8*)(xP + (size_t)(y0c * Ww + x1c) * 16);
        const u16x8* q10 = (const u16x8*)(xP + (size_t)(y1c * Ww + x0c) * 16);
        const u16x8* q11 = (const u16x8*)(xP + (size_t)(y1c * Ww + x1c) * 16);
        const u16x8 a00 = q00[0], b00 = q00[1];
        const u16x8 a01 = q01[0], b01 = q01[1];
        const u16x8 a10 = q10[0], b10 = q10[1];
        const u16x8 a11 = q11[0], b11 = q11[1];
#pragma unroll
        for (int c = 0; c < 8; ++c) {
          const float s = vget(a00, b00, c) * w00 + vget(a01, b01, c) * w01 +
                          vget(a10, b10, c) * w10 + vget(a11, b11, c) * w11;
          s0[c] = f2bf(s);
        }
#pragma unroll
        for (int c = 8; c < 16; ++c) {
          const float s = vget(a00, b00, c) * w00 + vget(a01, b01, c) * w01 +
                          vget(a10, b10, c) * w10 + vget(a11, b11, c) * w11;
          s1[c - 8] = f2bf(s);
        }
      }
      *(u16x8*)(myB + ti * 32) = s0;
      *(u16x8*)(myB + ti * 32 + 16) = s1;
    }
    // MFMA over this K=32 chunk: wave-local pixels, no barrier needed.
#pragma unroll
    for (int n = 0; n < 4; ++n) {
      const bf16x8 bfr =
          *(const bf16x8*)(sB + (wv * 64 + n * 16 + lm) * 80 + lq * 16);
      acc[n] = __builtin_amdgcn_mfma_f32_16x16x32_bf16(afr[pair], bfr, acc[n],
                                                       0, 0, 0);
    }
  }

  // epilogue: +bias; C layout col(pixel)=lm, row(out)=lq*4+r
  const float4 bv = *(const float4*)(bias + g * 16 + lq * 4);
#pragma unroll
  for (int n = 0; n < 4; ++n) {
    const int pixl = wv * 64 + n * 16 + lm;
    const int gpix = (ty0 + (pixl >> 4)) * Ww + tx0 + (pixl & 15);
    const f32x4 v = acc[n];
    if (NCHW_OUT) {
      float* oB = outF + (size_t)(b * 64 + g * 16 + lq * 4) * NPIX + gpix;
      oB[0] = v[0] + bv.x;
      oB[NPIX] = v[1] + bv.y;
      oB[2 * NPIX] = v[2] + bv.z;
      oB[3 * NPIX] = v[3] + bv.w;
    } else {
      ushort4 pk;
      pk.x = f2bf(v[0] + bv.x);
      pk.y = f2bf(v[1] + bv.y);
      pk.z = f2bf(v[2] + bv.z);
      pk.w = f2bf(v[3] + bv.w);
      *(ushort4*)(outH + ((size_t)(b * 4 + g) * NPIX + gpix) * 16 + lq * 4) =
          pk;
    }
  }
}

// ---------------------------------------------------------------------------

extern "C" void kernel_launch(void* const* d_in, const int* in_sizes, int n_in,
                              void* d_out, int out_size, void* d_ws,
                              size_t ws_size, hipStream_t stream) {
  const float* Fref = (const float*)d_in[0];
  const float* Fmov1 = (const float*)d_in[1];
  const float* Fmov2 = (const float*)d_in[2];
  const float* cr_w = (const float*)d_in[3];
  const float* cr_b = (const float*)d_in[4];
  const float* offw[4] = {(const float*)d_in[5], (const float*)d_in[7],
                          (const float*)d_in[9], (const float*)d_in[11]};
  const float* offb[4] = {(const float*)d_in[6], (const float*)d_in[8],
                          (const float*)d_in[10], (const float*)d_in[12]};
  const float* dw[4] = {(const float*)d_in[13], (const float*)d_in[15],
                        (const float*)d_in[17], (const float*)d_in[19]};
  const float* db[4] = {(const float*)d_in[14], (const float*)d_in[16],
                        (const float*)d_in[18], (const float*)d_in[20]};

  float* out0 = (float*)d_out;
  float* out1 = out0 + (size_t)NB * 64 * NPIX;

  char* p = (char*)d_ws;
  auto carve = [&](size_t bytes) {
    void* r = p;
    p += (bytes + 255) & ~(size_t)255;
    return r;
  };
  unsigned short* crIn = (unsigned short*)carve((size_t)NB * NPIX * 128 * 2);
  unsigned short* fmovG = (unsigned short*)carve((size_t)NB * NPIX * 64 * 2);
  unsigned short* feaA = (unsigned short*)carve((size_t)NB * NPIX * 64 * 2);
  unsigned short* feaB = (unsigned short*)carve((size_t)NB * NPIX * 64 * 2);
  unsigned short* offB = (unsigned short*)carve((size_t)NB * NPIX * 80 * 2);
  unsigned short* wcrT = (unsigned short*)carve((size_t)9 * 64 * 128 * 2);
  unsigned short* woffT[4];
  for (int i = 0; i < 4; ++i)
    woffT[i] = (unsigned short*)carve((size_t)9 * 80 * 64 * 2);
  unsigned short* dwP[4];
  for (int i = 0; i < 4; ++i)
    dwP[i] = (unsigned short*)carve((size_t)4 * 5 * 16 * 32 * 2);

  prep_convw_kernel<<<(9 * 64 * 128 + 255) / 256, 256, 0, stream>>>(
      cr_w, wcrT, 64, 64, 128);
  for (int i = 0; i < 4; ++i) {
    prep_convw_kernel<<<(9 * 80 * 64 + 255) / 256, 256, 0, stream>>>(
        offw[i], woffT[i], 72, 80, 64);
    prep_dwmfma_kernel<<<(4 * 5 * 16 * 32 + 255) / 256, 256, 0, stream>>>(
        dw[i], dwP[i]);
  }

  const dim3 cgrid(64, NB), cblk(512);
  const dim3 dgrid(64, 4, NB), dblk(256);

  for (int br = 0; br < 2; ++br) {
    const float* fm = br ? Fmov2 : Fmov1;
    float* outp = br ? out1 : out0;
    to_cl_kernel<<<NB * NPIX / 256, 256, 0, stream>>>(Fref, fm, crIn, fmovG);
    // fea = conv(crIn, cr)                 -> feaA (group-split)
    convmfma_kernel<128, 64, 64, 64, false, true>
        <<<cgrid, cblk, 0, stream>>>(crIn, wcrT, cr_b, feaA);
    // off1; fea = deform(feaA, off1, d1)   -> feaB
    convmfma_kernel<64, 80, 72, 80, true, false>
        <<<cgrid, cblk, 0, stream>>>(feaA, woffT[0], offb[0], offB);
    deform4_kernel<false>
        <<<dgrid, dblk, 0, stream>>>(feaA, offB, dwP[0], db[0], nullptr, feaB);
    // off2; fea = deform(feaB, off2, d2)   -> feaA
    convmfma_kernel<64, 80, 72, 80, true, false>
        <<<cgrid, cblk, 0, stream>>>(feaB, woffT[1], offb[1], offB);
    deform4_kernel<false>
        <<<dgrid, dblk, 0, stream>>>(feaB, offB, dwP[1], db[1], nullptr, feaA);
    // off3 from feaA; fea = deform(fmovG, off3, d3) -> feaB
    convmfma_kernel<64, 80, 72, 80, true, false>
        <<<cgrid, cblk, 0, stream>>>(feaA, woffT[2], offb[2], offB);
    deform4_kernel<false>
        <<<dgrid, dblk, 0, stream>>>(fmovG, offB, dwP[2], db[2], nullptr, feaB);
    // off4; out = deform(feaB, off4, d4)   -> d_out (f32 NCHW)
    convmfma_kernel<64, 80, 72, 80, true, false>
        <<<cgrid, cblk, 0, stream>>>(feaB, woffT[3], offb[3], offB);
    deform4_kernel<true>
        <<<dgrid, dblk, 0, stream>>>(feaB, offB, dwP[3], db[3], outp, nullptr);
  }
}

// Round 5
// 301.353 us; speedup vs baseline: 9.9569x; 1.2233x over previous
//
#include <hip/hip_runtime.h>

// AlignmentNet round 5: branch-batched (b2 = branch*4+b, "batch 8") pipeline:
// 11 kernels total. Group-split CL bf16 [b2][g][pix][16] everywhere; fused
// single prep kernel; MFMA convs + barrier-free MFMA deform.

using bf16x8 = __attribute__((ext_vector_type(8))) short;
using u16x8  = __attribute__((ext_vector_type(8))) unsigned short;
using f32x4  = __attribute__((ext_vector_type(4))) float;

static constexpr int Hh = 128, Ww = 128, NB = 4, NPIX = Hh * Ww;
static constexpr int BB = 8;  // batch*branches

__device__ __forceinline__ unsigned short f2bf(float f) {
  unsigned u = __float_as_uint(f);
  u += 0x7fffu + ((u >> 16) & 1u);   // round-to-nearest-even
  return (unsigned short)(u >> 16);
}
__device__ __forceinline__ float bf2f(unsigned short h) {
  return __uint_as_float(((unsigned)h) << 16);
}

// ---------------------------------------------------------------------------
// Fused weight prep: blockIdx.y selects tensor.
//  0: cr (cop=64,cin=128) -> [t][co][ci] bf16
//  1-4: off_i (cop=80, co_real=72, cin=64) -> [t][co][ci] bf16 (zero-pad)
//  5-8: dw_i (64,16,3,3) -> [g][pair][o][kk] bf16, tap 9 zero-padded
// ---------------------------------------------------------------------------
struct PrepPtrs {
  const float* cw[5];
  unsigned short* cd[5];
  const float* dw[4];
  unsigned short* dd[4];
};

__global__ __launch_bounds__(256) void prep_all_kernel(PrepPtrs pp) {
  const int which = blockIdx.y;
  const int i = blockIdx.x * 256 + threadIdx.x;
  if (which == 0) {
    if (i >= 9 * 64 * 128) return;
    const int cin = 128, cop = 64;
    const int ci = i % cin, co = (i / cin) % cop, t = i / (cin * cop);
    pp.cd[0][i] = f2bf(pp.cw[0][((size_t)co * cin + ci) * 9 + t]);
  } else if (which <= 4) {
    if (i >= 9 * 80 * 64) return;
    const int cin = 64, cop = 80, co_real = 72;
    const int ci = i % cin, co = (i / cin) % cop, t = i / (cin * cop);
    float v = (co < co_real) ? pp.cw[which][((size_t)co * cin + ci) * 9 + t]
                             : 0.f;
    pp.cd[which][i] = f2bf(v);
  } else {
    if (i >= 4 * 5 * 16 * 32) return;
    const int kk = i & 31, o = (i >> 5) & 15, pair = (i >> 9) % 5;
    const int g = i / 2560;
    const int t = pair * 2 + (kk >> 4), c = kk & 15;
    float v = (t < 9) ? pp.dw[which - 5][(size_t)((g * 16 + o) * 16 + c) * 9 + t]
                      : 0.f;
    pp.dd[which - 5][i] = f2bf(v);
  }
}

// ---------------------------------------------------------------------------
// NCHW f32 -> group-split bf16: frefG [4][4][pix][16], fmovG [8][4][pix][16]
// (b2 0-3 = Fmov1, 4-7 = Fmov2).
// ---------------------------------------------------------------------------
__global__ __launch_bounds__(256) void to_gs_kernel(
    const float* __restrict__ Fref, const float* __restrict__ Fm1,
    const float* __restrict__ Fm2, unsigned short* __restrict__ frefG,
    unsigned short* __restrict__ fmovG) {
  const int t = blockIdx.x * 256 + threadIdx.x;  // over BB*NPIX
  const int b2 = t >> 14, pix = t & (NPIX - 1);
  const float* fm = (b2 < 4 ? Fm1 : Fm2) + (size_t)(b2 & 3) * 64 * NPIX + pix;
  for (int c8 = 0; c8 < 8; ++c8) {
    u16x8 v;
#pragma unroll
    for (int j = 0; j < 8; ++j) v[j] = f2bf(fm[(size_t)(c8 * 8 + j) * NPIX]);
    *(u16x8*)(fmovG + ((size_t)(b2 * 4 + (c8 >> 1)) * NPIX + pix) * 16 +
              (c8 & 1) * 8) = v;
  }
  if (b2 < 4) {
    const float* fr = Fref + (size_t)b2 * 64 * NPIX + pix;
    for (int c8 = 0; c8 < 8; ++c8) {
      u16x8 v;
#pragma unroll
      for (int j = 0; j < 8; ++j) v[j] = f2bf(fr[(size_t)(c8 * 8 + j) * NPIX]);
      *(u16x8*)(frefG + ((size_t)(b2 * 4 + (c8 >> 1)) * NPIX + pix) * 16 +
                (c8 & 1) * 8) = v;
    }
  }
}

// ---------------------------------------------------------------------------
// MFMA conv 3x3 pad 1. Inputs are group-split [b'][4][pix][16] with batch
// index (b & bmask). 64-ch chunk 0 from in0, chunk 1 (CIN=128) from in1.
// OUT_GS: group-split out; else pixel-major [b][pix][OST].
// Grid: (64 tiles, BB), block 512 (8 waves).
// ---------------------------------------------------------------------------
template <int CIN, int COP, int CO_REAL, int OST, bool OUT_GS>
__global__ __launch_bounds__(512) void convmfma_kernel(
    const unsigned short* __restrict__ in0, int bmask0,
    const unsigned short* __restrict__ in1, int bmask1,
    const unsigned short* __restrict__ wT,   // [9][COP][CIN] bf16
    const float* __restrict__ biasP,         // [CO_REAL]
    unsigned short* __restrict__ out) {
  constexpr int COF = COP / 16;
  constexpr int NCH = CIN / 64;
  __shared__ unsigned short sA[9 * COP * 64];
  __shared__ unsigned short sB[324 * 64];

  const int tile = blockIdx.x, b = blockIdx.y;
  const int ty0 = (tile >> 3) << 4, tx0 = (tile & 7) << 4;
  const int tid = threadIdx.x;
  const int wv = tid >> 6, l = tid & 63;
  const int lm = l & 15, lq = l >> 4;

  f32x4 acc[COF][2];
#pragma unroll
  for (int cf = 0; cf < COF; ++cf)
#pragma unroll
    for (int pf = 0; pf < 2; ++pf) acc[cf][pf] = (f32x4){0.f, 0.f, 0.f, 0.f};

  const unsigned short* base0 = in0 + (size_t)(b & bmask0) * 4 * NPIX * 16;
  const unsigned short* base1 =
      (NCH > 1) ? in1 + (size_t)(b & bmask1) * 4 * NPIX * 16 : nullptr;

  for (int ch = 0; ch < NCH; ++ch) {
    const unsigned short* inB = (ch == 0) ? base0 : base1;
    const int cinBase = ch * 64;
    for (int q = tid; q < 324 * 8; q += 512) {
      const int pix = q >> 3, ci8 = q & 7;
      const int r = pix / 18, c = pix - r * 18;
      const int gy = ty0 - 1 + r, gx = tx0 - 1 + c;
      u16x8 v;
      if (gy >= 0 && gy < Hh && gx >= 0 && gx < Ww) {
        v = *(const u16x8*)(inB + ((size_t)(ci8 >> 1) * NPIX + gy * Ww + gx) *
                                      16 + (ci8 & 1) * 8);
      } else {
#pragma unroll
        for (int j = 0; j < 8; ++j) v[j] = 0;
      }
      const int boff = pix * 128 + ((ci8 * 16) ^ ((pix & 7) << 4));
      *(u16x8*)((char*)sB + boff) = v;
    }
    for (int q = tid; q < 9 * COP * 8; q += 512) {
      const int ci8 = q & 7;
      const int co = (q >> 3) % COP;
      const int t = q / (8 * COP);
      u16x8 v = *(const u16x8*)(wT + (size_t)(t * COP + co) * CIN + cinBase +
                                ci8 * 8);
      const int aoff = (t * COP + co) * 128 + ((ci8 * 16) ^ ((co & 7) << 4));
      *(u16x8*)((char*)sA + aoff) = v;
    }
    __syncthreads();
    for (int t = 0; t < 9; ++t) {
      const int dy = t / 3, dx = t - dy * 3;
#pragma unroll
      for (int kc = 0; kc < 2; ++kc) {
        bf16x8 afr[COF];
#pragma unroll
        for (int cf = 0; cf < COF; ++cf) {
          const int co = cf * 16 + lm;
          const int aoff =
              (t * COP + co) * 128 + ((kc * 64 + lq * 16) ^ ((co & 7) << 4));
          afr[cf] = *(const bf16x8*)((const char*)sA + aoff);
        }
#pragma unroll
        for (int pf = 0; pf < 2; ++pf) {
          const int pix = wv * 32 + pf * 16 + lm;
          const int spix = ((pix >> 4) + dy) * 18 + (pix & 15) + dx;
          const int boff =
              spix * 128 + ((kc * 64 + lq * 16) ^ ((spix & 7) << 4));
          const bf16x8 bfr = *(const bf16x8*)((const char*)sB + boff);
#pragma unroll
          for (int cf = 0; cf < COF; ++cf)
            acc[cf][pf] = __builtin_amdgcn_mfma_f32_16x16x32_bf16(
                afr[cf], bfr, acc[cf][pf], 0, 0, 0);
        }
      }
      if (NCH > 1 && t == 8) break;  // keep structure simple; no-op
    }
    __syncthreads();
  }
  unsigned short* outB = out + (size_t)b * NPIX * OST;
#pragma unroll
  for (int cf = 0; cf < COF; ++cf) {
    const int co0 = cf * 16 + lq * 4;
    if (co0 >= CO_REAL) continue;
    const float4 bv = *(const float4*)(biasP + co0);
#pragma unroll
    for (int pf = 0; pf < 2; ++pf) {
      const int pix = wv * 32 + pf * 16 + lm;
      const int gpix = (ty0 + (pix >> 4)) * Ww + tx0 + (pix & 15);
      const f32x4 v = acc[cf][pf];
      ushort4 pk;
      pk.x = f2bf(v[0] + bv.x);
      pk.y = f2bf(v[1] + bv.y);
      pk.z = f2bf(v[2] + bv.z);
      pk.w = f2bf(v[3] + bv.w);
      if (OUT_GS)
        *(ushort4*)(out + ((size_t)(b * 4 + cf) * NPIX + gpix) * 16 + lq * 4) =
            pk;
      else
        *(ushort4*)(outB + (size_t)gpix * OST + co0) = pk;
    }
  }
}

// ---------------------------------------------------------------------------
// MFMA deform: x group-split [b2][g][pix][16] bf16; offsets [b2][pix][80];
// thread = pixel; per tap-pair writes K=32 chunk to LDS (stride 80B), wave
// mfma's its own 64 pixels (no barrier). Grid: (64, G, BB), block 256.
// ---------------------------------------------------------------------------
__device__ __forceinline__ float vget(const u16x8& a, const u16x8& b, int c) {
  return bf2f((c < 8) ? (unsigned short)a[c] : (unsigned short)b[c - 8]);
}

template <bool NCHW_OUT>
__global__ __launch_bounds__(256, 4) void deform5_kernel(
    const unsigned short* __restrict__ x,    // [b2][g][pix][16] bf16
    const unsigned short* __restrict__ off,  // [b2][pix][80] bf16
    const unsigned short* __restrict__ dwP,  // [4][5][16][32] bf16
    const float* __restrict__ bias,          // [64]
    float* __restrict__ outF, unsigned short* __restrict__ outH) {
  __shared__ char sB[256 * 80];
  const int tile = blockIdx.x, g = blockIdx.y, b = blockIdx.z;
  const int ty0 = (tile >> 3) << 4, tx0 = (tile & 7) << 4;
  const int tid = threadIdx.x;
  const int l = tid & 63, wv = tid >> 6;
  const int lm = l & 15, lq = l >> 4;
  const int y = ty0 + (tid >> 4), xx = tx0 + (tid & 15);

  bf16x8 afr[5];
#pragma unroll
  for (int p = 0; p < 5; ++p)
    afr[p] = *(const bf16x8*)(dwP + ((size_t)(g * 5 + p) * 16 + lm) * 32 +
                              lq * 8);

  f32x4 acc[4];
#pragma unroll
  for (int n = 0; n < 4; ++n) acc[n] = (f32x4){0.f, 0.f, 0.f, 0.f};

  const unsigned short* xP = x + (size_t)(b * 4 + g) * NPIX * 16;
  const unsigned short* offP =
      off + (size_t)(b * NPIX + y * Ww + xx) * 80 + g * 18;
  char* myB = sB + tid * 80;

  unsigned od[9];
#pragma unroll
  for (int t = 0; t < 9; ++t) od[t] = *(const unsigned*)(offP + 2 * t);

#pragma unroll
  for (int pair = 0; pair < 5; ++pair) {
#pragma unroll
    for (int ti = 0; ti < 2; ++ti) {
      const int t = pair * 2 + ti;
      u16x8 s0, s1;
#pragma unroll
      for (int j = 0; j < 8; ++j) { s0[j] = 0; s1[j] = 0; }
      if (t < 9) {
        const unsigned odw = od[t < 9 ? t : 0];
        const float dy = __uint_as_float(odw << 16);
        const float dx = __uint_as_float(odw & 0xffff0000u);
        const float py = dy + (float)(y - 2 + 2 * (t / 3));
        const float px = dx + (float)(xx - 2 + 2 * (t % 3));
        const float fy = floorf(py), fx = floorf(px);
        const int y0 = (int)fy, x0 = (int)fx;
        const int y1 = y0 + 1, x1 = x0 + 1;
        const float ly = py - fy, lx = px - fx;
        float w00 = (1.f - ly) * (1.f - lx), w01 = (1.f - ly) * lx;
        float w10 = ly * (1.f - lx), w11 = ly * lx;
        const bool vy0 = (y0 >= 0) && (y0 < Hh), vy1 = (y1 >= 0) && (y1 < Hh);
        const bool vx0 = (x0 >= 0) && (x0 < Ww), vx1 = (x1 >= 0) && (x1 < Ww);
        w00 = (vy0 && vx0) ? w00 : 0.f;
        w01 = (vy0 && vx1) ? w01 : 0.f;
        w10 = (vy1 && vx0) ? w10 : 0.f;
        w11 = (vy1 && vx1) ? w11 : 0.f;
        const int y0c = min(max(y0, 0), Hh - 1), y1c = min(max(y1, 0), Hh - 1);
        const int x0c = min(max(x0, 0), Ww - 1), x1c = min(max(x1, 0), Ww - 1);
        const u16x8* q00 = (const u16x8*)(xP + (size_t)(y0c * Ww + x0c) * 16);
        const u16x8* q01 = (const u16x8*)(xP + (size_t)(y0c * Ww + x1c) * 16);
        const u16x8* q10 = (const u16x8*)(xP + (size_t)(y1c * Ww + x0c) * 16);
        const u16x8* q11 = (const u16x8*)(xP + (size_t)(y1c * Ww + x1c) * 16);
        const u16x8 a00 = q00[0], b00 = q00[1];
        const u16x8 a01 = q01[0], b01 = q01[1];
        const u16x8 a10 = q10[0], b10 = q10[1];
        const u16x8 a11 = q11[0], b11 = q11[1];
#pragma unroll
        for (int c = 0; c < 8; ++c) {
          const float s = vget(a00, b00, c) * w00 + vget(a01, b01, c) * w01 +
                          vget(a10, b10, c) * w10 + vget(a11, b11, c) * w11;
          s0[c] = f2bf(s);
        }
#pragma unroll
        for (int c = 8; c < 16; ++c) {
          const float s = vget(a00, b00, c) * w00 + vget(a01, b01, c) * w01 +
                          vget(a10, b10, c) * w10 + vget(a11, b11, c) * w11;
          s1[c - 8] = f2bf(s);
        }
      }
      *(u16x8*)(myB + ti * 32) = s0;
      *(u16x8*)(myB + ti * 32 + 16) = s1;
    }
#pragma unroll
    for (int n = 0; n < 4; ++n) {
      const bf16x8 bfr =
          *(const bf16x8*)(sB + (wv * 64 + n * 16 + lm) * 80 + lq * 16);
      acc[n] = __builtin_amdgcn_mfma_f32_16x16x32_bf16(afr[pair], bfr, acc[n],
                                                       0, 0, 0);
    }
  }

  const float4 bv = *(const float4*)(bias + g * 16 + lq * 4);
#pragma unroll
  for (int n = 0; n < 4; ++n) {
    const int pixl = wv * 64 + n * 16 + lm;
    const int gpix = (ty0 + (pixl >> 4)) * Ww + tx0 + (pixl & 15);
    const f32x4 v = acc[n];
    if (NCHW_OUT) {
      float* oB = outF + (size_t)(b * 64 + g * 16 + lq * 4) * NPIX + gpix;
      oB[0] = v[0] + bv.x;
      oB[NPIX] = v[1] + bv.y;
      oB[2 * NPIX] = v[2] + bv.z;
      oB[3 * NPIX] = v[3] + bv.w;
    } else {
      ushort4 pk;
      pk.x = f2bf(v[0] + bv.x);
      pk.y = f2bf(v[1] + bv.y);
      pk.z = f2bf(v[2] + bv.z);
      pk.w = f2bf(v[3] + bv.w);
      *(ushort4*)(outH + ((size_t)(b * 4 + g) * NPIX + gpix) * 16 + lq * 4) =
          pk;
    }
  }
}

// ---------------------------------------------------------------------------

extern "C" void kernel_launch(void* const* d_in, const int* in_sizes, int n_in,
                              void* d_out, int out_size, void* d_ws,
                              size_t ws_size, hipStream_t stream) {
  const float* Fref = (const float*)d_in[0];
  const float* Fmov1 = (const float*)d_in[1];
  const float* Fmov2 = (const float*)d_in[2];
  const float* cr_w = (const float*)d_in[3];
  const float* cr_b = (const float*)d_in[4];
  const float* offw[4] = {(const float*)d_in[5], (const float*)d_in[7],
                          (const float*)d_in[9], (const float*)d_in[11]};
  const float* offb[4] = {(const float*)d_in[6], (const float*)d_in[8],
                          (const float*)d_in[10], (const float*)d_in[12]};
  const float* dw[4] = {(const float*)d_in[13], (const float*)d_in[15],
                        (const float*)d_in[17], (const float*)d_in[19]};
  const float* db[4] = {(const float*)d_in[14], (const float*)d_in[16],
                        (const float*)d_in[18], (const float*)d_in[20]};

  char* p = (char*)d_ws;
  auto carve = [&](size_t bytes) {
    void* r = p;
    p += (bytes + 255) & ~(size_t)255;
    return r;
  };
  unsigned short* frefG = (unsigned short*)carve((size_t)4 * 4 * NPIX * 16 * 2);
  unsigned short* fmovG = (unsigned short*)carve((size_t)BB * 4 * NPIX * 16 * 2);
  unsigned short* feaA = (unsigned short*)carve((size_t)BB * 4 * NPIX * 16 * 2);
  unsigned short* feaB = (unsigned short*)carve((size_t)BB * 4 * NPIX * 16 * 2);
  unsigned short* offB = (unsigned short*)carve((size_t)BB * NPIX * 80 * 2);
  unsigned short* wcrT = (unsigned short*)carve((size_t)9 * 64 * 128 * 2);
  unsigned short* woffT[4];
  for (int i = 0; i < 4; ++i)
    woffT[i] = (unsigned short*)carve((size_t)9 * 80 * 64 * 2);
  unsigned short* dwP[4];
  for (int i = 0; i < 4; ++i)
    dwP[i] = (unsigned short*)carve((size_t)4 * 5 * 16 * 32 * 2);

  // ---- fused weight prep
  PrepPtrs pp;
  pp.cw[0] = cr_w;
  pp.cd[0] = wcrT;
  for (int i = 0; i < 4; ++i) {
    pp.cw[i + 1] = offw[i];
    pp.cd[i + 1] = woffT[i];
    pp.dw[i] = dw[i];
    pp.dd[i] = dwP[i];
  }
  prep_all_kernel<<<dim3(288, 9), 256, 0, stream>>>(pp);

  // ---- input conversion (both branches)
  to_gs_kernel<<<BB * NPIX / 256, 256, 0, stream>>>(Fref, Fmov1, Fmov2, frefG,
                                                    fmovG);

  const dim3 cgrid(64, BB), cblk(512);
  const dim3 dgrid(64, 4, BB), dblk(256);
  float* outF = (float*)d_out;  // [b2][64][H][W], b2 0-3 = branch1, 4-7 = br2

  // fea = conv([Fref|Fmov], cr)            -> feaA (GS)
  convmfma_kernel<128, 64, 64, 0, true><<<cgrid, cblk, 0, stream>>>(
      frefG, 3, fmovG, 7, wcrT, cr_b, feaA);
  // off1; fea = deform(feaA, off1, d1)     -> feaB
  convmfma_kernel<64, 80, 72, 80, false><<<cgrid, cblk, 0, stream>>>(
      feaA, 7, nullptr, 0, woffT[0], offb[0], offB);
  deform5_kernel<false>
      <<<dgrid, dblk, 0, stream>>>(feaA, offB, dwP[0], db[0], nullptr, feaB);
  // off2; fea = deform(feaB, off2, d2)     -> feaA
  convmfma_kernel<64, 80, 72, 80, false><<<cgrid, cblk, 0, stream>>>(
      feaB, 7, nullptr, 0, woffT[1], offb[1], offB);
  deform5_kernel<false>
      <<<dgrid, dblk, 0, stream>>>(feaB, offB, dwP[1], db[1], nullptr, feaA);
  // off3 from feaA; fea = deform(fmovG, off3, d3) -> feaB
  convmfma_kernel<64, 80, 72, 80, false><<<cgrid, cblk, 0, stream>>>(
      feaA, 7, nullptr, 0, woffT[2], offb[2], offB);
  deform5_kernel<false>
      <<<dgrid, dblk, 0, stream>>>(fmovG, offB, dwP[2], db[2], nullptr, feaB);
  // off4; out = deform(feaB, off4, d4)     -> d_out (f32 NCHW, b2-indexed)
  convmfma_kernel<64, 80, 72, 80, false><<<cgrid, cblk, 0, stream>>>(
      feaB, 7, nullptr, 0, woffT[3], offb[3], offB);
  deform5_kernel<true>
      <<<dgrid, dblk, 0, stream>>>(feaB, offB, dwP[3], db[3], outF, nullptr);
}

// Round 6
// 285.564 us; speedup vs baseline: 10.5075x; 1.0553x over previous
//
#include <hip/hip_runtime.h>

// AlignmentNet round 6: deform samples from an LDS-staged 28x28 window
// (per tile,group) with rare global fallback; branch-batched pipeline,
// group-split CL bf16 layouts, MFMA convs + barrier-light MFMA deform.

using bf16x8 = __attribute__((ext_vector_type(8))) short;
using u16x8  = __attribute__((ext_vector_type(8))) unsigned short;
using f32x4  = __attribute__((ext_vector_type(4))) float;

static constexpr int Hh = 128, Ww = 128, NB = 4, NPIX = Hh * Ww;
static constexpr int BB = 8;  // batch*branches

__device__ __forceinline__ unsigned short f2bf(float f) {
  unsigned u = __float_as_uint(f);
  u += 0x7fffu + ((u >> 16) & 1u);   // round-to-nearest-even
  return (unsigned short)(u >> 16);
}
__device__ __forceinline__ float bf2f(unsigned short h) {
  return __uint_as_float(((unsigned)h) << 16);
}

// ---------------------------------------------------------------------------
// Fused weight prep (blockIdx.y selects tensor; see round 5).
// ---------------------------------------------------------------------------
struct PrepPtrs {
  const float* cw[5];
  unsigned short* cd[5];
  const float* dw[4];
  unsigned short* dd[4];
};

__global__ __launch_bounds__(256) void prep_all_kernel(PrepPtrs pp) {
  const int which = blockIdx.y;
  const int i = blockIdx.x * 256 + threadIdx.x;
  if (which == 0) {
    if (i >= 9 * 64 * 128) return;
    const int cin = 128, cop = 64;
    const int ci = i % cin, co = (i / cin) % cop, t = i / (cin * cop);
    pp.cd[0][i] = f2bf(pp.cw[0][((size_t)co * cin + ci) * 9 + t]);
  } else if (which <= 4) {
    if (i >= 9 * 80 * 64) return;
    const int cin = 64, cop = 80, co_real = 72;
    const int ci = i % cin, co = (i / cin) % cop, t = i / (cin * cop);
    float v = (co < co_real) ? pp.cw[which][((size_t)co * cin + ci) * 9 + t]
                             : 0.f;
    pp.cd[which][i] = f2bf(v);
  } else {
    if (i >= 4 * 5 * 16 * 32) return;
    const int kk = i & 31, o = (i >> 5) & 15, pair = (i >> 9) % 5;
    const int g = i / 2560;
    const int t = pair * 2 + (kk >> 4), c = kk & 15;
    float v = (t < 9) ? pp.dw[which - 5][(size_t)((g * 16 + o) * 16 + c) * 9 + t]
                      : 0.f;
    pp.dd[which - 5][i] = f2bf(v);
  }
}

// ---------------------------------------------------------------------------
// NCHW f32 -> group-split bf16: frefG [4][4][pix][16], fmovG [8][4][pix][16]
// ---------------------------------------------------------------------------
__global__ __launch_bounds__(256) void to_gs_kernel(
    const float* __restrict__ Fref, const float* __restrict__ Fm1,
    const float* __restrict__ Fm2, unsigned short* __restrict__ frefG,
    unsigned short* __restrict__ fmovG) {
  const int t = blockIdx.x * 256 + threadIdx.x;  // over BB*NPIX
  const int b2 = t >> 14, pix = t & (NPIX - 1);
  const float* fm = (b2 < 4 ? Fm1 : Fm2) + (size_t)(b2 & 3) * 64 * NPIX + pix;
  for (int c8 = 0; c8 < 8; ++c8) {
    u16x8 v;
#pragma unroll
    for (int j = 0; j < 8; ++j) v[j] = f2bf(fm[(size_t)(c8 * 8 + j) * NPIX]);
    *(u16x8*)(fmovG + ((size_t)(b2 * 4 + (c8 >> 1)) * NPIX + pix) * 16 +
              (c8 & 1) * 8) = v;
  }
  if (b2 < 4) {
    const float* fr = Fref + (size_t)b2 * 64 * NPIX + pix;
    for (int c8 = 0; c8 < 8; ++c8) {
      u16x8 v;
#pragma unroll
      for (int j = 0; j < 8; ++j) v[j] = f2bf(fr[(size_t)(c8 * 8 + j) * NPIX]);
      *(u16x8*)(frefG + ((size_t)(b2 * 4 + (c8 >> 1)) * NPIX + pix) * 16 +
                (c8 & 1) * 8) = v;
    }
  }
}

// ---------------------------------------------------------------------------
// MFMA conv 3x3 pad 1 (group-split inputs; see round 5).
// ---------------------------------------------------------------------------
template <int CIN, int COP, int CO_REAL, int OST, bool OUT_GS>
__global__ __launch_bounds__(512) void convmfma_kernel(
    const unsigned short* __restrict__ in0, int bmask0,
    const unsigned short* __restrict__ in1, int bmask1,
    const unsigned short* __restrict__ wT,   // [9][COP][CIN] bf16
    const float* __restrict__ biasP,         // [CO_REAL]
    unsigned short* __restrict__ out) {
  constexpr int COF = COP / 16;
  constexpr int NCH = CIN / 64;
  __shared__ unsigned short sA[9 * COP * 64];
  __shared__ unsigned short sB[324 * 64];

  const int tile = blockIdx.x, b = blockIdx.y;
  const int ty0 = (tile >> 3) << 4, tx0 = (tile & 7) << 4;
  const int tid = threadIdx.x;
  const int wv = tid >> 6, l = tid & 63;
  const int lm = l & 15, lq = l >> 4;

  f32x4 acc[COF][2];
#pragma unroll
  for (int cf = 0; cf < COF; ++cf)
#pragma unroll
    for (int pf = 0; pf < 2; ++pf) acc[cf][pf] = (f32x4){0.f, 0.f, 0.f, 0.f};

  const unsigned short* base0 = in0 + (size_t)(b & bmask0) * 4 * NPIX * 16;
  const unsigned short* base1 =
      (NCH > 1) ? in1 + (size_t)(b & bmask1) * 4 * NPIX * 16 : nullptr;

  for (int ch = 0; ch < NCH; ++ch) {
    const unsigned short* inB = (ch == 0) ? base0 : base1;
    for (int q = tid; q < 324 * 8; q += 512) {
      const int pix = q >> 3, ci8 = q & 7;
      const int r = pix / 18, c = pix - r * 18;
      const int gy = ty0 - 1 + r, gx = tx0 - 1 + c;
      u16x8 v;
      if (gy >= 0 && gy < Hh && gx >= 0 && gx < Ww) {
        v = *(const u16x8*)(inB + ((size_t)(ci8 >> 1) * NPIX + gy * Ww + gx) *
                                      16 + (ci8 & 1) * 8);
      } else {
#pragma unroll
        for (int j = 0; j < 8; ++j) v[j] = 0;
      }
      const int boff = pix * 128 + ((ci8 * 16) ^ ((pix & 7) << 4));
      *(u16x8*)((char*)sB + boff) = v;
    }
    for (int q = tid; q < 9 * COP * 8; q += 512) {
      const int ci8 = q & 7;
      const int co = (q >> 3) % COP;
      const int t = q / (8 * COP);
      u16x8 v = *(const u16x8*)(wT + (size_t)(t * COP + co) * CIN + ch * 64 +
                                ci8 * 8);
      const int aoff = (t * COP + co) * 128 + ((ci8 * 16) ^ ((co & 7) << 4));
      *(u16x8*)((char*)sA + aoff) = v;
    }
    __syncthreads();
    for (int t = 0; t < 9; ++t) {
      const int dy = t / 3, dx = t - dy * 3;
#pragma unroll
      for (int kc = 0; kc < 2; ++kc) {
        bf16x8 afr[COF];
#pragma unroll
        for (int cf = 0; cf < COF; ++cf) {
          const int co = cf * 16 + lm;
          const int aoff =
              (t * COP + co) * 128 + ((kc * 64 + lq * 16) ^ ((co & 7) << 4));
          afr[cf] = *(const bf16x8*)((const char*)sA + aoff);
        }
#pragma unroll
        for (int pf = 0; pf < 2; ++pf) {
          const int pix = wv * 32 + pf * 16 + lm;
          const int spix = ((pix >> 4) + dy) * 18 + (pix & 15) + dx;
          const int boff =
              spix * 128 + ((kc * 64 + lq * 16) ^ ((spix & 7) << 4));
          const bf16x8 bfr = *(const bf16x8*)((const char*)sB + boff);
#pragma unroll
          for (int cf = 0; cf < COF; ++cf)
            acc[cf][pf] = __builtin_amdgcn_mfma_f32_16x16x32_bf16(
                afr[cf], bfr, acc[cf][pf], 0, 0, 0);
        }
      }
    }
    __syncthreads();
  }
  unsigned short* outB = out + (size_t)b * NPIX * OST;
#pragma unroll
  for (int cf = 0; cf < COF; ++cf) {
    const int co0 = cf * 16 + lq * 4;
    if (co0 >= CO_REAL) continue;
    const float4 bv = *(const float4*)(biasP + co0);
#pragma unroll
    for (int pf = 0; pf < 2; ++pf) {
      const int pix = wv * 32 + pf * 16 + lm;
      const int gpix = (ty0 + (pix >> 4)) * Ww + tx0 + (pix & 15);
      const f32x4 v = acc[cf][pf];
      ushort4 pk;
      pk.x = f2bf(v[0] + bv.x);
      pk.y = f2bf(v[1] + bv.y);
      pk.z = f2bf(v[2] + bv.z);
      pk.w = f2bf(v[3] + bv.w);
      if (OUT_GS)
        *(ushort4*)(out + ((size_t)(b * 4 + cf) * NPIX + gpix) * 16 + lq * 4) =
            pk;
      else
        *(ushort4*)(outB + (size_t)gpix * OST + co0) = pk;
    }
  }
}

// ---------------------------------------------------------------------------
// MFMA deform v6: stage clamped 28x28x16ch window (|off|<=3) in LDS; bilinear
// corners are ds_read_b128 with per-lane global fallback for out-of-window
// samples. Sample->LDS(K=32 chunks)->wave-local MFMA (no barrier after stage).
// Grid: (64 tiles, G, BB), block 256.
// ---------------------------------------------------------------------------
static constexpr int WROW = 912;  // 28*32 + 16 pad, multiple of 16

__device__ __forceinline__ float vget(const u16x8& a, const u16x8& b, int c) {
  return bf2f((c < 8) ? (unsigned short)a[c] : (unsigned short)b[c - 8]);
}

template <bool NCHW_OUT>
__global__ __launch_bounds__(256, 4) void deform6_kernel(
    const unsigned short* __restrict__ x,    // [b2][g][pix][16] bf16
    const unsigned short* __restrict__ off,  // [b2][pix][80] bf16
    const unsigned short* __restrict__ dwP,  // [4][5][16][32] bf16
    const float* __restrict__ bias,          // [64]
    float* __restrict__ outF, unsigned short* __restrict__ outH) {
  __shared__ char sX[28 * WROW];
  __shared__ char sB[256 * 80];
  const int tile = blockIdx.x, g = blockIdx.y, b = blockIdx.z;
  const int ty0 = (tile >> 3) << 4, tx0 = (tile & 7) << 4;
  const int wy0 = ty0 - 6, wx0 = tx0 - 6;
  const int tid = threadIdx.x;
  const int l = tid & 63, wv = tid >> 6;
  const int lm = l & 15, lq = l >> 4;
  const int y = ty0 + (tid >> 4), xx = tx0 + (tid & 15);

  const unsigned short* xP = x + (size_t)(b * 4 + g) * NPIX * 16;

  // ---- stage window (clamped rows/cols; duplicates at borders are fine)
  for (int i = tid; i < 28 * 28; i += 256) {
    const int r = i / 28, c = i - r * 28;
    const int iy = min(max(wy0 + r, 0), Hh - 1);
    const int ix = min(max(wx0 + c, 0), Ww - 1);
    const u16x8* s = (const u16x8*)(xP + (size_t)(iy * Ww + ix) * 16);
    char* d = sX + r * WROW + c * 32;
    *(u16x8*)d = s[0];
    *(u16x8*)(d + 16) = s[1];
  }

  bf16x8 afr[5];
#pragma unroll
  for (int p = 0; p < 5; ++p)
    afr[p] = *(const bf16x8*)(dwP + ((size_t)(g * 5 + p) * 16 + lm) * 32 +
                              lq * 8);

  f32x4 acc[4];
#pragma unroll
  for (int n = 0; n < 4; ++n) acc[n] = (f32x4){0.f, 0.f, 0.f, 0.f};

  const unsigned short* offP =
      off + (size_t)(b * NPIX + y * Ww + xx) * 80 + g * 18;
  char* myB = sB + tid * 80;

  unsigned od[9];
#pragma unroll
  for (int t = 0; t < 9; ++t) od[t] = *(const unsigned*)(offP + 2 * t);

  __syncthreads();  // window ready

#pragma unroll
  for (int pair = 0; pair < 5; ++pair) {
#pragma unroll
    for (int ti = 0; ti < 2; ++ti) {
      const int t = pair * 2 + ti;
      u16x8 s0, s1;
#pragma unroll
      for (int j = 0; j < 8; ++j) { s0[j] = 0; s1[j] = 0; }
      if (t < 9) {
        const unsigned odw = od[t < 9 ? t : 0];
        const float dy = __uint_as_float(odw << 16);
        const float dx = __uint_as_float(odw & 0xffff0000u);
        const float py = dy + (float)(y - 2 + 2 * (t / 3));
        const float px = dx + (float)(xx - 2 + 2 * (t % 3));
        const float fy = floorf(py), fx = floorf(px);
        const int y0 = (int)fy, x0 = (int)fx;
        const int y1 = y0 + 1, x1 = x0 + 1;
        const float ly = py - fy, lx = px - fx;
        float w00 = (1.f - ly) * (1.f - lx), w01 = (1.f - ly) * lx;
        float w10 = ly * (1.f - lx), w11 = ly * lx;
        const bool vy0 = (y0 >= 0) && (y0 < Hh), vy1 = (y1 >= 0) && (y1 < Hh);
        const bool vx0 = (x0 >= 0) && (x0 < Ww), vx1 = (x1 >= 0) && (x1 < Ww);
        w00 = (vy0 && vx0) ? w00 : 0.f;
        w01 = (vy0 && vx1) ? w01 : 0.f;
        w10 = (vy1 && vx0) ? w10 : 0.f;
        w11 = (vy1 && vx1) ? w11 : 0.f;
        const int y0c = min(max(y0, 0), Hh - 1), y1c = min(max(y1, 0), Hh - 1);
        const int x0c = min(max(x0, 0), Ww - 1), x1c = min(max(x1, 0), Ww - 1);

        u16x8 a00, b00, a01, b01, a10, b10, a11, b11;
        const bool inWin = (y0 >= wy0) && (y1 <= wy0 + 27) && (x0 >= wx0) &&
                           (x1 <= wx0 + 27);
        if (__builtin_expect(inWin, 1)) {
          const char* p00 = sX + (y0c - wy0) * WROW + (x0c - wx0) * 32;
          const char* p01 = sX + (y0c - wy0) * WROW + (x1c - wx0) * 32;
          const char* p10 = sX + (y1c - wy0) * WROW + (x0c - wx0) * 32;
          const char* p11 = sX + (y1c - wy0) * WROW + (x1c - wx0) * 32;
          a00 = *(const u16x8*)p00; b00 = *(const u16x8*)(p00 + 16);
          a01 = *(const u16x8*)p01; b01 = *(const u16x8*)(p01 + 16);
          a10 = *(const u16x8*)p10; b10 = *(const u16x8*)(p10 + 16);
          a11 = *(const u16x8*)p11; b11 = *(const u16x8*)(p11 + 16);
        } else {
          const u16x8* q00 = (const u16x8*)(xP + (size_t)(y0c * Ww + x0c) * 16);
          const u16x8* q01 = (const u16x8*)(xP + (size_t)(y0c * Ww + x1c) * 16);
          const u16x8* q10 = (const u16x8*)(xP + (size_t)(y1c * Ww + x0c) * 16);
          const u16x8* q11 = (const u16x8*)(xP + (size_t)(y1c * Ww + x1c) * 16);
          a00 = q00[0]; b00 = q00[1];
          a01 = q01[0]; b01 = q01[1];
          a10 = q10[0]; b10 = q10[1];
          a11 = q11[0]; b11 = q11[1];
        }
#pragma unroll
        for (int c = 0; c < 8; ++c) {
          const float s = vget(a00, b00, c) * w00 + vget(a01, b01, c) * w01 +
                          vget(a10, b10, c) * w10 + vget(a11, b11, c) * w11;
          s0[c] = f2bf(s);
        }
#pragma unroll
        for (int c = 8; c < 16; ++c) {
          const float s = vget(a00, b00, c) * w00 + vget(a01, b01, c) * w01 +
                          vget(a10, b10, c) * w10 + vget(a11, b11, c) * w11;
          s1[c - 8] = f2bf(s);
        }
      }
      *(u16x8*)(myB + ti * 32) = s0;
      *(u16x8*)(myB + ti * 32 + 16) = s1;
    }
#pragma unroll
    for (int n = 0; n < 4; ++n) {
      const bf16x8 bfr =
          *(const bf16x8*)(sB + (wv * 64 + n * 16 + lm) * 80 + lq * 16);
      acc[n] = __builtin_amdgcn_mfma_f32_16x16x32_bf16(afr[pair], bfr, acc[n],
                                                       0, 0, 0);
    }
  }

  const float4 bv = *(const float4*)(bias + g * 16 + lq * 4);
#pragma unroll
  for (int n = 0; n < 4; ++n) {
    const int pixl = wv * 64 + n * 16 + lm;
    const int gpix = (ty0 + (pixl >> 4)) * Ww + tx0 + (pixl & 15);
    const f32x4 v = acc[n];
    if (NCHW_OUT) {
      float* oB = outF + (size_t)(b * 64 + g * 16 + lq * 4) * NPIX + gpix;
      oB[0] = v[0] + bv.x;
      oB[NPIX] = v[1] + bv.y;
      oB[2 * NPIX] = v[2] + bv.z;
      oB[3 * NPIX] = v[3] + bv.w;
    } else {
      ushort4 pk;
      pk.x = f2bf(v[0] + bv.x);
      pk.y = f2bf(v[1] + bv.y);
      pk.z = f2bf(v[2] + bv.z);
      pk.w = f2bf(v[3] + bv.w);
      *(ushort4*)(outH + ((size_t)(b * 4 + g) * NPIX + gpix) * 16 + lq * 4) =
          pk;
    }
  }
}

// ---------------------------------------------------------------------------

extern "C" void kernel_launch(void* const* d_in, const int* in_sizes, int n_in,
                              void* d_out, int out_size, void* d_ws,
                              size_t ws_size, hipStream_t stream) {
  const float* Fref = (const float*)d_in[0];
  const float* Fmov1 = (const float*)d_in[1];
  const float* Fmov2 = (const float*)d_in[2];
  const float* cr_w = (const float*)d_in[3];
  const float* cr_b = (const float*)d_in[4];
  const float* offw[4] = {(const float*)d_in[5], (const float*)d_in[7],
                          (const float*)d_in[9], (const float*)d_in[11]};
  const float* offb[4] = {(const float*)d_in[6], (const float*)d_in[8],
                          (const float*)d_in[10], (const float*)d_in[12]};
  const float* dw[4] = {(const float*)d_in[13], (const float*)d_in[15],
                        (const float*)d_in[17], (const float*)d_in[19]};
  const float* db[4] = {(const float*)d_in[14], (const float*)d_in[16],
                        (const float*)d_in[18], (const float*)d_in[20]};

  char* p = (char*)d_ws;
  auto carve = [&](size_t bytes) {
    void* r = p;
    p += (bytes + 255) & ~(size_t)255;
    return r;
  };
  unsigned short* frefG = (unsigned short*)carve((size_t)4 * 4 * NPIX * 16 * 2);
  unsigned short* fmovG = (unsigned short*)carve((size_t)BB * 4 * NPIX * 16 * 2);
  unsigned short* feaA = (unsigned short*)carve((size_t)BB * 4 * NPIX * 16 * 2);
  unsigned short* feaB = (unsigned short*)carve((size_t)BB * 4 * NPIX * 16 * 2);
  unsigned short* offB = (unsigned short*)carve((size_t)BB * NPIX * 80 * 2);
  unsigned short* wcrT = (unsigned short*)carve((size_t)9 * 64 * 128 * 2);
  unsigned short* woffT[4];
  for (int i = 0; i < 4; ++i)
    woffT[i] = (unsigned short*)carve((size_t)9 * 80 * 64 * 2);
  unsigned short* dwP[4];
  for (int i = 0; i < 4; ++i)
    dwP[i] = (unsigned short*)carve((size_t)4 * 5 * 16 * 32 * 2);

  PrepPtrs pp;
  pp.cw[0] = cr_w;
  pp.cd[0] = wcrT;
  for (int i = 0; i < 4; ++i) {
    pp.cw[i + 1] = offw[i];
    pp.cd[i + 1] = woffT[i];
    pp.dw[i] = dw[i];
    pp.dd[i] = dwP[i];
  }
  prep_all_kernel<<<dim3(288, 9), 256, 0, stream>>>(pp);

  to_gs_kernel<<<BB * NPIX / 256, 256, 0, stream>>>(Fref, Fmov1, Fmov2, frefG,
                                                    fmovG);

  const dim3 cgrid(64, BB), cblk(512);
  const dim3 dgrid(64, 4, BB), dblk(256);
  float* outF = (float*)d_out;  // [b2][64][H][W], b2 0-3 = branch1, 4-7 = br2

  // fea = conv([Fref|Fmov], cr)            -> feaA (GS)
  convmfma_kernel<128, 64, 64, 0, true><<<cgrid, cblk, 0, stream>>>(
      frefG, 3, fmovG, 7, wcrT, cr_b, feaA);
  // off1; fea = deform(feaA, off1, d1)     -> feaB
  convmfma_kernel<64, 80, 72, 80, false><<<cgrid, cblk, 0, stream>>>(
      feaA, 7, nullptr, 0, woffT[0], offb[0], offB);
  deform6_kernel<false>
      <<<dgrid, dblk, 0, stream>>>(feaA, offB, dwP[0], db[0], nullptr, feaB);
  // off2; fea = deform(feaB, off2, d2)     -> feaA
  convmfma_kernel<64, 80, 72, 80, false><<<cgrid, cblk, 0, stream>>>(
      feaB, 7, nullptr, 0, woffT[1], offb[1], offB);
  deform6_kernel<false>
      <<<dgrid, dblk, 0, stream>>>(feaB, offB, dwP[1], db[1], nullptr, feaA);
  // off3 from feaA; fea = deform(fmovG, off3, d3) -> feaB
  convmfma_kernel<64, 80, 72, 80, false><<<cgrid, cblk, 0, stream>>>(
      feaA, 7, nullptr, 0, woffT[2], offb[2], offB);
  deform6_kernel<false>
      <<<dgrid, dblk, 0, stream>>>(fmovG, offB, dwP[2], db[2], nullptr, feaB);
  // off4; out = deform(feaB, off4, d4)     -> d_out (f32 NCHW, b2-indexed)
  convmfma_kernel<64, 80, 72, 80, false><<<cgrid, cblk, 0, stream>>>(
      feaB, 7, nullptr, 0, woffT[3], offb[3], offB);
  deform6_kernel<true>
      <<<dgrid, dblk, 0, stream>>>(feaB, offB, dwP[3], db[3], outF, nullptr);
}